// Round 5
// baseline (357.801 us; speedup 1.0000x reference)
//
#include <hip/hip_runtime.h>
#include <hip/hip_bf16.h>
#include <cstdint>
#include <cstddef>

namespace {

constexpr int BB  = 4;      // batch
constexpr int LL  = 2048;   // seq
constexpr int DM  = 256;    // d_model
constexpr int DI  = 512;    // d_inner
constexpr int DFF = 1024;
constexpr float EPSV = 1e-5f;
constexpr int BL  = BB * LL;     // 8192 rows per direction
constexpr int M2  = 2 * BL;      // 16384 rows (both dirs)
constexpr int NCH = 8;           // scan chunks
constexpr int CHL = LL / NCH;    // 256 timesteps per chunk
constexpr int NCHAIN = 2 * BB * DI;   // 4096 scan chains

typedef __attribute__((ext_vector_type(8))) short bf16x8;
typedef __attribute__((ext_vector_type(4))) float f32x4;

__device__ __forceinline__ float fsilu(float v) { return v / (1.f + __expf(-v)); }

__device__ __forceinline__ short f2bf(float f) {
  union { float f; uint32_t u; } v; v.f = f;
  uint32_t r = (v.u + 0x7fffu + ((v.u >> 16) & 1u)) >> 16;
  return (short)r;
}

__device__ __forceinline__ void gld16(const short* g, short* l) {
  __builtin_amdgcn_global_load_lds(
      (const __attribute__((address_space(1))) void*)g,
      (__attribute__((address_space(3))) void*)l, 16, 0, 0);
}

// ---------------------------------------------------------------------------
// fused f32 -> bf16 convert for x + 4 weight tensors (one launch)
// block ranges: [0,2048) x | [2048,2560) in_w | [2560,2816) out_w
//               [2816,3072) w1 | [3072,3328) w2
// ---------------------------------------------------------------------------
__global__ __launch_bounds__(256) void cvt5_kernel(
    const float* __restrict__ s0, const float* __restrict__ s1,
    const float* __restrict__ s2, const float* __restrict__ s3,
    const float* __restrict__ s4,
    short* __restrict__ o0, short* __restrict__ o1, short* __restrict__ o2,
    short* __restrict__ o3, short* __restrict__ o4)
{
  int bid = blockIdx.x;
  const float* s; short* o; int i;
  if (bid < 2048)      { s = s0; o = o0; i = bid; }
  else if (bid < 2560) { s = s1; o = o1; i = bid - 2048; }
  else if (bid < 2816) { s = s2; o = o2; i = bid - 2560; }
  else if (bid < 3072) { s = s3; o = o3; i = bid - 2816; }
  else                 { s = s4; o = o4; i = bid - 3072; }
  int off = (i * 256 + threadIdx.x) * 4;
  float4 v = *reinterpret_cast<const float4*>(s + off);
  ushort4 u;
  u.x = (unsigned short)f2bf(v.x); u.y = (unsigned short)f2bf(v.y);
  u.z = (unsigned short)f2bf(v.z); u.w = (unsigned short)f2bf(v.w);
  *reinterpret_cast<ushort4*>(o + off) = u;
}

// ---------------------------------------------------------------------------
// bf16 MFMA GEMM, 128x128 tile, BK=32, 4 waves of 64x64, fp32 accum.
// ---------------------------------------------------------------------------
template <int EP>
__global__ __launch_bounds__(256) void mgemm(
    const short* __restrict__ A, const short* __restrict__ W,
    float* __restrict__ Cf, short* __restrict__ Ch, int N, int K,
    const float* __restrict__ P0, const float* __restrict__ P1,
    const float* __restrict__ P2, const float* __restrict__ P3,
    const float* __restrict__ P4, const float* __restrict__ P5)
{
  __shared__ short As[128 * 32];
  __shared__ short Bs[128 * 32];
  const int tid  = threadIdx.x;
  const int lane = tid & 63, wv = tid >> 6;
  const int wrow = (wv >> 1) * 64, wcol = (wv & 1) * 64;
  const int row0 = blockIdx.y * 128, col0 = blockIdx.x * 128;
  const int dir  = (EP == 0 || EP == 1) ? (row0 >= BL ? 1 : 0) : 0;
  const short* Wp = W + (size_t)dir * (size_t)N * (size_t)K;

  f32x4 acc[4][4];
#pragma unroll
  for (int m = 0; m < 4; ++m)
#pragma unroll
    for (int n = 0; n < 4; ++n) acc[m][n] = (f32x4){0.f, 0.f, 0.f, 0.f};

  for (int k0 = 0; k0 < K; k0 += 32) {
#pragma unroll
    for (int s = 0; s < 2; ++s) {
      int f = s * 256 + wv * 64 + lane;      // [0,512)
      int rr = f >> 2, kc = f & 3;           // tile row, 16B chunk along k
      const short* asrc;
      if (EP == 0) {
        int r  = row0 + rr;
        int rb = r & (BL - 1);
        int b = rb >> 11, t = rb & (LL - 1);
        int torig = dir ? (LL - 1 - t) : t;
        asrc = A + ((size_t)(b * LL + torig)) * K + k0 + kc * 8;
      } else {
        asrc = A + (size_t)(row0 + rr) * K + k0 + kc * 8;
      }
      const short* bsrc = Wp + (size_t)(col0 + rr) * K + k0 + kc * 8;
      gld16(asrc, &As[(s * 256 + wv * 64) * 8]);   // wave-uniform LDS base
      gld16(bsrc, &Bs[(s * 256 + wv * 64) * 8]);
    }
    __syncthreads();
    bf16x8 af[4], bfr[4];
    const int krow = (lane >> 4) * 8;
#pragma unroll
    for (int m = 0; m < 4; ++m)
      af[m] = *reinterpret_cast<const bf16x8*>(&As[(wrow + m * 16 + (lane & 15)) * 32 + krow]);
#pragma unroll
    for (int n = 0; n < 4; ++n)
      bfr[n] = *reinterpret_cast<const bf16x8*>(&Bs[(wcol + n * 16 + (lane & 15)) * 32 + krow]);
#pragma unroll
    for (int m = 0; m < 4; ++m)
#pragma unroll
      for (int n = 0; n < 4; ++n)
        acc[m][n] = __builtin_amdgcn_mfma_f32_16x16x32_bf16(af[m], bfr[n], acc[m][n], 0, 0, 0);
    __syncthreads();
  }

  // epilogue: C/D layout col=lane&15, row=(lane>>4)*4+reg
#pragma unroll
  for (int m = 0; m < 4; ++m) {
#pragma unroll
    for (int i = 0; i < 4; ++i) {
      int r = row0 + wrow + m * 16 + (lane >> 4) * 4 + i;
      size_t obase;
      if (EP == 1) {
        int rb = r & (BL - 1);
        int b = rb >> 11, t = rb & (LL - 1);
        int torig = dir ? (LL - 1 - t) : t;
        obase = ((size_t)(dir * BB + b) * LL + torig) * DM;
      } else {
        obase = (size_t)r * N;
      }
#pragma unroll
      for (int n = 0; n < 4; ++n) {
        int c = col0 + wcol + n * 16 + (lane & 15);
        float val = acc[m][n][i];
        if (EP == 1) {
          int o = dir * DM + c;
          val = (val - P2[o]) * rsqrtf(P3[o] + EPSV) * P0[o] + P1[o];
          Cf[obase + c] = val;
        } else if (EP == 2) {
          val = fmaxf(val + P0[c], 0.f);
          Ch[obase + c] = f2bf(val);
        } else if (EP == 3) {
          val = val + P0[c];
          int o = 2 * DM + c;
          val = (val - P3[o]) * rsqrtf(P4[o] + EPSV) * P1[o] + P2[o];
          val += P5[obase + c];
          Cf[obase + c] = val;
        } else {
          Cf[obase + c] = val;
        }
      }
    }
  }
}

// ---------------------------------------------------------------------------
// causal depthwise conv (taps=4) + bias + SiLU, float4 over channels.
// ---------------------------------------------------------------------------
__global__ __launch_bounds__(256) void conv_silu_kernel(
    const float* __restrict__ XZ, const float* __restrict__ cw,
    const float* __restrict__ cb, float* __restrict__ XI)
{
  int idx = blockIdx.x * 256 + threadIdx.x;   // [0, 16.7M/4)
  int dq = (idx & 127) * 4;                   // channel group base
  int r  = idx >> 7;                          // (dir*4+b)*2048 + t
  int t  = r & (LL - 1);
  int db = r >> 11;
  int dir = db >> 2;
  size_t base = (size_t)db * LL * 1024 + dq;  // x-half of XZ, t'=0
  float4 wc0 = *reinterpret_cast<const float4*>(cw + (size_t)(dir * DI + dq + 0) * 4);
  float4 wc1 = *reinterpret_cast<const float4*>(cw + (size_t)(dir * DI + dq + 1) * 4);
  float4 wc2 = *reinterpret_cast<const float4*>(cw + (size_t)(dir * DI + dq + 2) * 4);
  float4 wc3 = *reinterpret_cast<const float4*>(cw + (size_t)(dir * DI + dq + 3) * 4);
  float4 bv  = *reinterpret_cast<const float4*>(cb + dir * DI + dq);
  float a0 = bv.x, a1 = bv.y, a2 = bv.z, a3 = bv.w;
#pragma unroll
  for (int j = 0; j < 4; ++j) {
    int tp = t - 3 + j;
    if (tp >= 0) {
      float4 xv = *reinterpret_cast<const float4*>(XZ + base + (size_t)tp * 1024);
      float w0j = j == 0 ? wc0.x : j == 1 ? wc0.y : j == 2 ? wc0.z : wc0.w;
      float w1j = j == 0 ? wc1.x : j == 1 ? wc1.y : j == 2 ? wc1.z : wc1.w;
      float w2j = j == 0 ? wc2.x : j == 1 ? wc2.y : j == 2 ? wc2.z : wc2.w;
      float w3j = j == 0 ? wc3.x : j == 1 ? wc3.y : j == 2 ? wc3.z : wc3.w;
      a0 = fmaf(w0j, xv.x, a0); a1 = fmaf(w1j, xv.y, a1);
      a2 = fmaf(w2j, xv.z, a2); a3 = fmaf(w3j, xv.w, a3);
    }
  }
  float4 o = make_float4(fsilu(a0), fsilu(a1), fsilu(a2), fsilu(a3));
  *reinterpret_cast<float4*>(XI + (size_t)r * DI + dq) = o;
}

// ---------------------------------------------------------------------------
// xproj: DBC(M2 x 48) = XI(M2 x 512) @ xproj_w(dir)^T.  64-row tiles, fp32.
// ---------------------------------------------------------------------------
__global__ __launch_bounds__(256) void xproj_kernel(
    const float* __restrict__ XI, const float* __restrict__ W, float* __restrict__ DBC)
{
  __shared__ __align__(16) float As[64 * 68];   // [k][row]
  __shared__ __align__(16) float Ws[64 * 52];   // [k][col]
  const int tid = threadIdx.x;
  const int row0 = blockIdx.x * 64;
  const int dir = row0 >= BL ? 1 : 0;
  const float* Wp = W + (size_t)dir * 48 * DI;
  const int TX = tid & 15, TY = tid >> 4;
  float acc[4][3];
#pragma unroll
  for (int i = 0; i < 4; ++i)
#pragma unroll
    for (int j = 0; j < 3; ++j) acc[i][j] = 0.f;

  for (int k0 = 0; k0 < DI; k0 += 64) {
#pragma unroll
    for (int s = 0; s < 4; ++s) {
      int f = tid + s * 256;
      int kq = f & 15, m = f >> 4;
      float4 v = *reinterpret_cast<const float4*>(XI + (size_t)(row0 + m) * DI + k0 + kq * 4);
      int kk = kq * 4;
      As[(kk + 0) * 68 + m] = v.x; As[(kk + 1) * 68 + m] = v.y;
      As[(kk + 2) * 68 + m] = v.z; As[(kk + 3) * 68 + m] = v.w;
    }
#pragma unroll
    for (int s = 0; s < 3; ++s) {
      int f = tid + s * 256;
      int kq = f & 15, n = f >> 4;
      float4 v = *reinterpret_cast<const float4*>(Wp + (size_t)n * DI + k0 + kq * 4);
      int kk = kq * 4;
      Ws[(kk + 0) * 52 + n] = v.x; Ws[(kk + 1) * 52 + n] = v.y;
      Ws[(kk + 2) * 52 + n] = v.z; Ws[(kk + 3) * 52 + n] = v.w;
    }
    __syncthreads();
    for (int k = 0; k < 64; ++k) {
      float a[4], b[3];
#pragma unroll
      for (int i = 0; i < 4; ++i) a[i] = As[k * 68 + TY * 4 + i];
#pragma unroll
      for (int j = 0; j < 3; ++j) b[j] = Ws[k * 52 + TX * 3 + j];
#pragma unroll
      for (int i = 0; i < 4; ++i)
#pragma unroll
        for (int j = 0; j < 3; ++j) acc[i][j] = fmaf(a[i], b[j], acc[i][j]);
    }
    __syncthreads();
  }
#pragma unroll
  for (int i = 0; i < 4; ++i)
#pragma unroll
    for (int j = 0; j < 3; ++j)
      DBC[(size_t)(row0 + TY * 4 + i) * 48 + TX * 3 + j] = acc[i][j];
}

// ---------------------------------------------------------------------------
// delta = softplus(dt @ dt_w^T + dt_b); one block per (dir,b,t) row
// ---------------------------------------------------------------------------
__global__ __launch_bounds__(256) void dtproj_kernel(
    const float* __restrict__ DBC, const float* __restrict__ dt_w,
    const float* __restrict__ dt_b, float* __restrict__ DELTA)
{
  int row = blockIdx.x;            // [0, 16384)
  int dir = row >> 13;
  __shared__ float dtv[16];
  if (threadIdx.x < 16) dtv[threadIdx.x] = DBC[(size_t)row * 48 + threadIdx.x];
  __syncthreads();
  for (int dd = threadIdx.x; dd < DI; dd += 256) {
    const float* wrow = dt_w + (size_t)(dir * DI + dd) * 16;
    float a = dt_b[dir * DI + dd];
#pragma unroll
    for (int r = 0; r < 16; ++r) a = fmaf(dtv[r], wrow[r], a);
    float sp = (a > 20.f) ? a : log1pf(__expf(a));
    DELTA[(size_t)row * DI + dd] = sp;
  }
}

// ---------------------------------------------------------------------------
// Chunked scan pass 1: per (chain,chunk) recurrence from h0=0 -> HEND, SDT.
// Transposed LDS windows [ch][t] (stride 20), register-cached inner loop.
// thread = (d:tid>>4, n:tid&15). grid 2048.
// ---------------------------------------------------------------------------
__global__ __launch_bounds__(256) void scan1_kernel(
    const float* __restrict__ DELTA, const float* __restrict__ XI,
    const float* __restrict__ DBC, const float* __restrict__ Alog,
    float* __restrict__ HEND, float* __restrict__ SDT)
{
  __shared__ float Dl[2][320], Xl[2][320], Bl[2][320];
  const int tid = threadIdx.x;
  const int lane = tid & 63, wv = tid >> 6;
  const int d = tid >> 4, n = tid & 15;
  const int blk = blockIdx.x & 255, chunk = blockIdx.x >> 8;
  const int chain0 = blk * 16;
  const int dir = chain0 >> 11, b = (chain0 >> 9) & 3;
  const int d0 = chain0 & 511;

  const float An = -__expf(Alog[((size_t)(dir * DI + d0 + d)) * 16 + n]);
  const size_t seq = (size_t)(dir * BB + b) * LL + chunk * CHL;
  const size_t baseDU = seq * DI;
  const size_t baseBC = seq * 48;

  const int st = lane >> 2, sq = lane & 3;   // stager: t, d-quad
  // prologue: stage window 0 (transposed into [ch][t])
  if (wv == 0) {
    float4 v = *reinterpret_cast<const float4*>(DELTA + baseDU + (size_t)st * DI + d0 + sq * 4);
    Dl[0][(sq*4+0)*20+st] = v.x; Dl[0][(sq*4+1)*20+st] = v.y;
    Dl[0][(sq*4+2)*20+st] = v.z; Dl[0][(sq*4+3)*20+st] = v.w;
  } else if (wv == 1) {
    float4 v = *reinterpret_cast<const float4*>(XI + baseDU + (size_t)st * DI + d0 + sq * 4);
    Xl[0][(sq*4+0)*20+st] = v.x; Xl[0][(sq*4+1)*20+st] = v.y;
    Xl[0][(sq*4+2)*20+st] = v.z; Xl[0][(sq*4+3)*20+st] = v.w;
  } else if (wv == 2) {
    float4 v = *reinterpret_cast<const float4*>(DBC + baseBC + (size_t)st * 48 + 16 + sq * 4);
    Bl[0][(sq*4+0)*20+st] = v.x; Bl[0][(sq*4+1)*20+st] = v.y;
    Bl[0][(sq*4+2)*20+st] = v.z; Bl[0][(sq*4+3)*20+st] = v.w;
  }
  __syncthreads();

  float h = 0.f, sdt = 0.f;
  for (int w = 0; w < CHL / 16; ++w) {
    const int bb = w & 1;
    float rdt[16], ru[16], rB[16];
#pragma unroll
    for (int q = 0; q < 4; ++q) {
      *reinterpret_cast<float4*>(&rdt[4*q]) = *reinterpret_cast<const float4*>(&Dl[bb][d*20 + 4*q]);
      *reinterpret_cast<float4*>(&ru[4*q])  = *reinterpret_cast<const float4*>(&Xl[bb][d*20 + 4*q]);
      *reinterpret_cast<float4*>(&rB[4*q])  = *reinterpret_cast<const float4*>(&Bl[bb][n*20 + 4*q]);
    }
    const bool more = (w + 1 < CHL / 16);
    float4 g = {};
    if (more) {
      int t = (w + 1) * 16 + st;
      if (wv == 0)      g = *reinterpret_cast<const float4*>(DELTA + baseDU + (size_t)t * DI + d0 + sq * 4);
      else if (wv == 1) g = *reinterpret_cast<const float4*>(XI + baseDU + (size_t)t * DI + d0 + sq * 4);
      else if (wv == 2) g = *reinterpret_cast<const float4*>(DBC + baseBC + (size_t)t * 48 + 16 + sq * 4);
    }
#pragma unroll
    for (int tt = 0; tt < 16; ++tt) {
      float dA = __expf(rdt[tt] * An);
      h = fmaf(dA, h, rdt[tt] * ru[tt] * rB[tt]);
      sdt += rdt[tt];
    }
    if (more) {
      if (wv == 0) {
        Dl[bb^1][(sq*4+0)*20+st] = g.x; Dl[bb^1][(sq*4+1)*20+st] = g.y;
        Dl[bb^1][(sq*4+2)*20+st] = g.z; Dl[bb^1][(sq*4+3)*20+st] = g.w;
      } else if (wv == 1) {
        Xl[bb^1][(sq*4+0)*20+st] = g.x; Xl[bb^1][(sq*4+1)*20+st] = g.y;
        Xl[bb^1][(sq*4+2)*20+st] = g.z; Xl[bb^1][(sq*4+3)*20+st] = g.w;
      } else if (wv == 2) {
        Bl[bb^1][(sq*4+0)*20+st] = g.x; Bl[bb^1][(sq*4+1)*20+st] = g.y;
        Bl[bb^1][(sq*4+2)*20+st] = g.z; Bl[bb^1][(sq*4+3)*20+st] = g.w;
      }
    }
    __syncthreads();
  }
  HEND[((size_t)chunk * NCHAIN + chain0 + d) * 16 + n] = h;
  if (n == 0) SDT[chunk * NCHAIN + chain0 + d] = sdt;
}

// ---------------------------------------------------------------------------
// pass 2: scan across chunks per chain. grid: 256 blocks.
// ---------------------------------------------------------------------------
__global__ __launch_bounds__(256) void scan2_kernel(
    const float* __restrict__ HEND, const float* __restrict__ SDT,
    const float* __restrict__ Alog, float* __restrict__ HINIT)
{
  const int tid = threadIdx.x;
  const int cl = tid >> 4, n = tid & 15;
  const int chain = blockIdx.x * 16 + cl;
  const int dir = chain >> 11;
  const int d   = chain & 511;
  const float An = -__expf(Alog[((size_t)(dir * DI + d)) * 16 + n]);
  float h = 0.f;
#pragma unroll
  for (int c = 0; c < NCH; ++c) {
    size_t o = ((size_t)c * NCHAIN + chain) * 16 + n;
    HINIT[o] = h;
    float ap = __expf(An * SDT[c * NCHAIN + chain]);
    h = fmaf(ap, h, HEND[o]);
  }
}

// ---------------------------------------------------------------------------
// pass 3: recurrence from HINIT + fused gate -> G16 bf16 (coalesced 8B).
// Register-cached windows; hc transpose per-wave-local; ex tile for output.
// ---------------------------------------------------------------------------
__global__ __launch_bounds__(256) void scan3_kernel(
    const float* __restrict__ DELTA, const float* __restrict__ XI,
    const float* __restrict__ DBC, const float* __restrict__ Alog,
    const float* __restrict__ HINIT, const float* __restrict__ XZ,
    const float* __restrict__ Dp, short* __restrict__ G16)
{
  __shared__ float Dl[2][320], Xl[2][320], Bl[2][320], Cl[2][320], Zl[2][320];
  __shared__ float hc[5312];      // [d:16] stride 332, [t:16] stride 20, [n:16]
  __shared__ float ex[4][68];     // per-wave output exchange
  const int tid = threadIdx.x;
  const int lane = tid & 63, wv = tid >> 6;
  const int d = tid >> 4, n = tid & 15;
  const int blk = blockIdx.x & 255, chunk = blockIdx.x >> 8;
  const int chain0 = blk * 16;
  const int dir = chain0 >> 11, b = (chain0 >> 9) & 3;
  const int d0 = chain0 & 511;

  const float An = -__expf(Alog[((size_t)(dir * DI + d0 + d)) * 16 + n]);
  const size_t seq = (size_t)(dir * BB + b) * LL + chunk * CHL;
  const size_t baseDU = seq * DI;
  const size_t baseBC = seq * 48;
  const float Dskip = Dp[dir * DI + d0 + d];

  float h = HINIT[((size_t)chunk * NCHAIN + chain0 + d) * 16 + n];

  const int st = lane >> 2, sq = lane & 3;
  // prologue: stage window 0
  if (wv == 0) {
    float4 v = *reinterpret_cast<const float4*>(DELTA + baseDU + (size_t)st * DI + d0 + sq * 4);
    Dl[0][(sq*4+0)*20+st] = v.x; Dl[0][(sq*4+1)*20+st] = v.y;
    Dl[0][(sq*4+2)*20+st] = v.z; Dl[0][(sq*4+3)*20+st] = v.w;
  } else if (wv == 1) {
    float4 v = *reinterpret_cast<const float4*>(XI + baseDU + (size_t)st * DI + d0 + sq * 4);
    Xl[0][(sq*4+0)*20+st] = v.x; Xl[0][(sq*4+1)*20+st] = v.y;
    Xl[0][(sq*4+2)*20+st] = v.z; Xl[0][(sq*4+3)*20+st] = v.w;
  } else if (wv == 2) {
    float4 v = *reinterpret_cast<const float4*>(DBC + baseBC + (size_t)st * 48 + 16 + sq * 4);
    Bl[0][(sq*4+0)*20+st] = v.x; Bl[0][(sq*4+1)*20+st] = v.y;
    Bl[0][(sq*4+2)*20+st] = v.z; Bl[0][(sq*4+3)*20+st] = v.w;
    float4 c = *reinterpret_cast<const float4*>(DBC + baseBC + (size_t)st * 48 + 32 + sq * 4);
    Cl[0][(sq*4+0)*20+st] = c.x; Cl[0][(sq*4+1)*20+st] = c.y;
    Cl[0][(sq*4+2)*20+st] = c.z; Cl[0][(sq*4+3)*20+st] = c.w;
  } else {
    float4 v = *reinterpret_cast<const float4*>(XZ + (seq + st) * 1024 + 512 + d0 + sq * 4);
    Zl[0][(sq*4+0)*20+st] = v.x; Zl[0][(sq*4+1)*20+st] = v.y;
    Zl[0][(sq*4+2)*20+st] = v.z; Zl[0][(sq*4+3)*20+st] = v.w;
  }
  __syncthreads();

  for (int w = 0; w < CHL / 16; ++w) {
    const int bb = w & 1;
    float rdt[16], ru[16], rB[16], rC[16];
#pragma unroll
    for (int q = 0; q < 4; ++q) {
      *reinterpret_cast<float4*>(&rdt[4*q]) = *reinterpret_cast<const float4*>(&Dl[bb][d*20 + 4*q]);
      *reinterpret_cast<float4*>(&ru[4*q])  = *reinterpret_cast<const float4*>(&Xl[bb][d*20 + 4*q]);
      *reinterpret_cast<float4*>(&rB[4*q])  = *reinterpret_cast<const float4*>(&Bl[bb][n*20 + 4*q]);
      *reinterpret_cast<float4*>(&rC[4*q])  = *reinterpret_cast<const float4*>(&Cl[bb][n*20 + 4*q]);
    }
    const bool more = (w + 1 < CHL / 16);
    float4 g = {}, g2 = {};
    if (more) {
      int t = (w + 1) * 16 + st;
      if (wv == 0)      g = *reinterpret_cast<const float4*>(DELTA + baseDU + (size_t)t * DI + d0 + sq * 4);
      else if (wv == 1) g = *reinterpret_cast<const float4*>(XI + baseDU + (size_t)t * DI + d0 + sq * 4);
      else if (wv == 2) {
        g  = *reinterpret_cast<const float4*>(DBC + baseBC + (size_t)t * 48 + 16 + sq * 4);
        g2 = *reinterpret_cast<const float4*>(DBC + baseBC + (size_t)t * 48 + 32 + sq * 4);
      } else {
        g = *reinterpret_cast<const float4*>(XZ + (seq + t) * 1024 + 512 + d0 + sq * 4);
      }
    }
    // serial recurrence, register-only; h* scatter into hc
#pragma unroll
    for (int tt = 0; tt < 16; ++tt) {
      float dA = __expf(rdt[tt] * An);
      h = fmaf(dA, h, rdt[tt] * ru[tt] * rB[tt]);
      hc[d * 332 + tt * 20 + n] = h * rC[tt];
    }
    __builtin_amdgcn_sched_barrier(0);
    // y(t=n, d) = sum over states
    float hv[16];
#pragma unroll
    for (int q = 0; q < 4; ++q)
      *reinterpret_cast<float4*>(&hv[4*q]) = *reinterpret_cast<const float4*>(&hc[d * 332 + n * 20 + 4*q]);
    float y = 0.f;
#pragma unroll
    for (int j = 0; j < 16; ++j) y += hv[j];
    float u_n = Xl[bb][d * 20 + n];
    float z_n = Zl[bb][d * 20 + n];
    float yy = (y + u_n * Dskip) * fsilu(z_n);
    ex[wv][n * 4 + (d & 3)] = yy;
    __builtin_amdgcn_sched_barrier(0);
    if (lane < 16) {
      float4 ev = *reinterpret_cast<const float4*>(&ex[wv][lane * 4]);
      ushort4 o;
      o.x = (unsigned short)f2bf(ev.x); o.y = (unsigned short)f2bf(ev.y);
      o.z = (unsigned short)f2bf(ev.z); o.w = (unsigned short)f2bf(ev.w);
      *reinterpret_cast<ushort4*>(G16 + baseDU + (size_t)(w * 16 + lane) * DI + d0 + wv * 4) = o;
    }
    if (more) {
      if (wv == 0) {
        Dl[bb^1][(sq*4+0)*20+st] = g.x; Dl[bb^1][(sq*4+1)*20+st] = g.y;
        Dl[bb^1][(sq*4+2)*20+st] = g.z; Dl[bb^1][(sq*4+3)*20+st] = g.w;
      } else if (wv == 1) {
        Xl[bb^1][(sq*4+0)*20+st] = g.x; Xl[bb^1][(sq*4+1)*20+st] = g.y;
        Xl[bb^1][(sq*4+2)*20+st] = g.z; Xl[bb^1][(sq*4+3)*20+st] = g.w;
      } else if (wv == 2) {
        Bl[bb^1][(sq*4+0)*20+st] = g.x;  Bl[bb^1][(sq*4+1)*20+st] = g.y;
        Bl[bb^1][(sq*4+2)*20+st] = g.z;  Bl[bb^1][(sq*4+3)*20+st] = g.w;
        Cl[bb^1][(sq*4+0)*20+st] = g2.x; Cl[bb^1][(sq*4+1)*20+st] = g2.y;
        Cl[bb^1][(sq*4+2)*20+st] = g2.z; Cl[bb^1][(sq*4+3)*20+st] = g2.w;
      } else {
        Zl[bb^1][(sq*4+0)*20+st] = g.x; Zl[bb^1][(sq*4+1)*20+st] = g.y;
        Zl[bb^1][(sq*4+2)*20+st] = g.z; Zl[bb^1][(sq*4+3)*20+st] = g.w;
      }
    }
    __syncthreads();
  }
}

// ---------------------------------------------------------------------------
// dual AddNorm combine: S16 = bf16(LN0(x+f) + LN1(x+bwd)). one block per (b,t).
// ---------------------------------------------------------------------------
__global__ __launch_bounds__(256) void ln_combine_kernel(
    const float* __restrict__ MOUT, const float* __restrict__ x,
    const float* __restrict__ ln_g, const float* __restrict__ ln_b,
    short* __restrict__ S16)
{
  int row = blockIdx.x;
  int m = threadIdx.x;
  size_t i0 = (size_t)row * DM + m;
  float xv = x[i0];
  float s1 = xv + MOUT[i0];
  float s2 = xv + MOUT[(size_t)BL * DM + i0];
  float a1 = s1, q1 = s1 * s1, a2 = s2, q2 = s2 * s2;
  for (int off = 32; off; off >>= 1) {
    a1 += __shfl_xor(a1, off); q1 += __shfl_xor(q1, off);
    a2 += __shfl_xor(a2, off); q2 += __shfl_xor(q2, off);
  }
  __shared__ float red[4][4];
  int w = m >> 6;
  if ((m & 63) == 0) { red[w][0] = a1; red[w][1] = q1; red[w][2] = a2; red[w][3] = q2; }
  __syncthreads();
  a1 = red[0][0] + red[1][0] + red[2][0] + red[3][0];
  q1 = red[0][1] + red[1][1] + red[2][1] + red[3][1];
  a2 = red[0][2] + red[1][2] + red[2][2] + red[3][2];
  q2 = red[0][3] + red[1][3] + red[2][3] + red[3][3];
  const float inv = 1.f / 256.f;
  float mu1 = a1 * inv, mu2 = a2 * inv;
  float v1 = q1 * inv - mu1 * mu1, v2 = q2 * inv - mu2 * mu2;
  float r1 = rsqrtf(v1 + EPSV), r2 = rsqrtf(v2 + EPSV);
  float out = (s1 - mu1) * r1 * ln_g[m] + ln_b[m] +
              (s2 - mu2) * r2 * ln_g[DM + m] + ln_b[DM + m];
  S16[i0] = f2bf(out);
}

}  // namespace

// ---------------------------------------------------------------------------
// workspace (floats):
//   XZ    @ 0          16,777,216  (2,B,L,1024)  [bf16 H16 after scan3]
//   XI    @ 16777216    8,388,608  (2,B,L,512)   [fp32 MOUT after out_proj]
//   DBC   @ 25165824      786,432  (2,B,L,48)
//   DELTA @ 25952256    8,388,608  (2,B,L,512)
//   YS    @ 34340864    8,388,608  [bf16 G16 from scan3; later bf16 S16]
//   X16   @ 42729472    1,048,576  (bf16 x)
//   W16   @ 43778048      655,360  (bf16 weights)
//   HEND  @ 44433408      524,288  (8,4096,16)
//   HINIT @ 44957696      524,288  (8,4096,16)
//   SDT   @ 45481984       32,768  (8,4096)
// total 45,514,752 floats = 182.1 MB
// ---------------------------------------------------------------------------
extern "C" void kernel_launch(void* const* d_in, const int* in_sizes, int n_in,
                              void* d_out, int out_size, void* d_ws, size_t ws_size,
                              hipStream_t stream) {
  (void)in_sizes; (void)n_in; (void)out_size; (void)ws_size;
  const float* x      = (const float*)d_in[0];
  const float* in_w   = (const float*)d_in[1];
  const float* conv_w = (const float*)d_in[2];
  const float* conv_b = (const float*)d_in[3];
  const float* xproj_w= (const float*)d_in[4];
  const float* dt_w   = (const float*)d_in[5];
  const float* dt_b   = (const float*)d_in[6];
  const float* Alog   = (const float*)d_in[7];
  const float* Dp     = (const float*)d_in[8];
  const float* out_w  = (const float*)d_in[9];
  const float* bn_g   = (const float*)d_in[10];
  const float* bn_b   = (const float*)d_in[11];
  const float* bn_m   = (const float*)d_in[12];
  const float* bn_v   = (const float*)d_in[13];
  const float* ln_g   = (const float*)d_in[14];
  const float* ln_b   = (const float*)d_in[15];
  const float* w1     = (const float*)d_in[16];
  const float* b1     = (const float*)d_in[17];
  const float* w2     = (const float*)d_in[18];
  const float* b2     = (const float*)d_in[19];

  float* ws    = (float*)d_ws;
  float* XZ    = ws;
  float* XI    = ws + 16777216;
  float* DBC   = ws + 25165824;
  float* DELTA = ws + 25952256;
  float* YS    = ws + 34340864;
  short* X16   = (short*)(ws + 42729472);
  short* W16   = (short*)(ws + 43778048);
  short* IN16  = W16;
  short* OUT16 = W16 + 524288;
  short* W1_16 = W16 + 786432;
  short* W2_16 = W16 + 1048576;
  float* HEND  = ws + 44433408;
  float* HINIT = ws + 44957696;
  float* SDT   = ws + 45481984;
  short* G16   = (short*)YS;          // scan3 output (YS region)
  float* MOUT  = XI;                  // XI dead after scan3
  short* S16   = (short*)YS;          // G16 dead after out_proj
  short* H16   = (short*)XZ;          // XZ dead after scan3
  float* OUT   = (float*)d_out;

  dim3 blk(256);

  // 0. bf16 conversions (x + 4 weight tensors, single launch)
  cvt5_kernel<<<3328, blk, 0, stream>>>(x, in_w, out_w, w1, w2,
      X16, IN16, OUT16, W1_16, W2_16);

  // 1. in_proj (both dirs, flip via row map) -> XZ fp32
  mgemm<0><<<dim3(8, 128), blk, 0, stream>>>(X16, IN16, XZ, nullptr, 1024, 256,
      nullptr, nullptr, nullptr, nullptr, nullptr, nullptr);
  // 2. depthwise conv + SiLU -> XI (float4)
  conv_silu_kernel<<<16384, blk, 0, stream>>>(XZ, conv_w, conv_b, XI);
  // 3. x_proj -> DBC
  xproj_kernel<<<256, blk, 0, stream>>>(XI, xproj_w, DBC);
  // 4. dt proj + softplus -> DELTA
  dtproj_kernel<<<16384, blk, 0, stream>>>(DBC, dt_w, dt_b, DELTA);
  // 5. chunked SSM scan, gate fused into pass 3 -> G16
  scan1_kernel<<<2048, blk, 0, stream>>>(DELTA, XI, DBC, Alog, HEND, SDT);
  scan2_kernel<<<256,  blk, 0, stream>>>(HEND, SDT, Alog, HINIT);
  scan3_kernel<<<2048, blk, 0, stream>>>(DELTA, XI, DBC, Alog, HINIT, XZ, Dp, G16);
  // 7. out_proj + BN(dir) + un-flip -> MOUT (fp32, overwrites XI)
  mgemm<1><<<dim3(2, 128), blk, 0, stream>>>(G16, OUT16, MOUT, nullptr, 256, 512,
      bn_g, bn_b, bn_m, bn_v, nullptr, nullptr);
  // 8. dual AddNorm combine -> S16 (bf16, overwrites G16 region)
  ln_combine_kernel<<<8192, blk, 0, stream>>>(MOUT, x, ln_g, ln_b, S16);
  // 9. FF1 (+bias, ReLU) -> H16 (bf16, overwrites XZ)
  mgemm<2><<<dim3(8, 64), blk, 0, stream>>>(S16, W1_16, nullptr, H16, 1024, 256,
      b1, nullptr, nullptr, nullptr, nullptr, nullptr);
  // 10. FF2 (+bias, BN[2], +x) -> OUT fp32
  mgemm<3><<<dim3(2, 64), blk, 0, stream>>>(H16, W2_16, OUT, nullptr, 256, 1024,
      b2, bn_g, bn_b, bn_m, bn_v, x);
}

// Round 6
// 317.839 us; speedup vs baseline: 1.1257x; 1.1257x over previous
//
#include <hip/hip_runtime.h>
#include <hip/hip_bf16.h>
#include <cstdint>
#include <cstddef>

namespace {

constexpr int BB  = 4;      // batch
constexpr int LL  = 2048;   // seq
constexpr int DM  = 256;    // d_model
constexpr int DI  = 512;    // d_inner
constexpr int DFF = 1024;
constexpr float EPSV = 1e-5f;
constexpr int BL  = BB * LL;     // 8192 rows per direction
constexpr int M2  = 2 * BL;      // 16384 rows (both dirs)
constexpr int NCH = 16;          // scan chunks
constexpr int CHL = LL / NCH;    // 128 timesteps per chunk
constexpr int NCHAIN = 2 * BB * DI;   // 4096 scan chains

typedef __attribute__((ext_vector_type(8))) short bf16x8;
typedef __attribute__((ext_vector_type(4))) float f32x4;

__device__ __forceinline__ float fsilu(float v) { return v / (1.f + __expf(-v)); }

__device__ __forceinline__ short f2bf(float f) {
  union { float f; uint32_t u; } v; v.f = f;
  uint32_t r = (v.u + 0x7fffu + ((v.u >> 16) & 1u)) >> 16;
  return (short)r;
}

__device__ __forceinline__ void gld16(const short* g, short* l) {
  __builtin_amdgcn_global_load_lds(
      (const __attribute__((address_space(1))) void*)g,
      (__attribute__((address_space(3))) void*)l, 16, 0, 0);
}

// quad (4-lane) sum via DPP quad_perm — pure VALU, no LDS traffic
__device__ __forceinline__ float quad_sum(float v) {
  int a = __builtin_amdgcn_update_dpp(0, __float_as_int(v), 0xB1, 0xF, 0xF, true); // xor1
  v += __int_as_float(a);
  int b = __builtin_amdgcn_update_dpp(0, __float_as_int(v), 0x4E, 0xF, 0xF, true); // xor2
  v += __int_as_float(b);
  return v;
}

// ---------------------------------------------------------------------------
// fused f32 -> bf16 convert for x + 4 weight tensors (one launch)
// ---------------------------------------------------------------------------
__global__ __launch_bounds__(256) void cvt5_kernel(
    const float* __restrict__ s0, const float* __restrict__ s1,
    const float* __restrict__ s2, const float* __restrict__ s3,
    const float* __restrict__ s4,
    short* __restrict__ o0, short* __restrict__ o1, short* __restrict__ o2,
    short* __restrict__ o3, short* __restrict__ o4)
{
  int bid = blockIdx.x;
  const float* s; short* o; int i;
  if (bid < 2048)      { s = s0; o = o0; i = bid; }
  else if (bid < 2560) { s = s1; o = o1; i = bid - 2048; }
  else if (bid < 2816) { s = s2; o = o2; i = bid - 2560; }
  else if (bid < 3072) { s = s3; o = o3; i = bid - 2816; }
  else                 { s = s4; o = o4; i = bid - 3072; }
  int off = (i * 256 + threadIdx.x) * 4;
  float4 v = *reinterpret_cast<const float4*>(s + off);
  ushort4 u;
  u.x = (unsigned short)f2bf(v.x); u.y = (unsigned short)f2bf(v.y);
  u.z = (unsigned short)f2bf(v.z); u.w = (unsigned short)f2bf(v.w);
  *reinterpret_cast<ushort4*>(o + off) = u;
}

// ---------------------------------------------------------------------------
// bf16 MFMA GEMM, 128x128 tile, BK=32, 4 waves of 64x64, fp32 accum.
// ---------------------------------------------------------------------------
template <int EP>
__global__ __launch_bounds__(256) void mgemm(
    const short* __restrict__ A, const short* __restrict__ W,
    float* __restrict__ Cf, short* __restrict__ Ch, int N, int K,
    const float* __restrict__ P0, const float* __restrict__ P1,
    const float* __restrict__ P2, const float* __restrict__ P3,
    const float* __restrict__ P4, const float* __restrict__ P5)
{
  __shared__ short As[128 * 32];
  __shared__ short Bs[128 * 32];
  const int tid  = threadIdx.x;
  const int lane = tid & 63, wv = tid >> 6;
  const int wrow = (wv >> 1) * 64, wcol = (wv & 1) * 64;
  const int row0 = blockIdx.y * 128, col0 = blockIdx.x * 128;
  const int dir  = (EP == 0 || EP == 1) ? (row0 >= BL ? 1 : 0) : 0;
  const short* Wp = W + (size_t)dir * (size_t)N * (size_t)K;

  f32x4 acc[4][4];
#pragma unroll
  for (int m = 0; m < 4; ++m)
#pragma unroll
    for (int n = 0; n < 4; ++n) acc[m][n] = (f32x4){0.f, 0.f, 0.f, 0.f};

  for (int k0 = 0; k0 < K; k0 += 32) {
#pragma unroll
    for (int s = 0; s < 2; ++s) {
      int f = s * 256 + wv * 64 + lane;      // [0,512)
      int rr = f >> 2, kc = f & 3;           // tile row, 16B chunk along k
      const short* asrc;
      if (EP == 0) {
        int r  = row0 + rr;
        int rb = r & (BL - 1);
        int b = rb >> 11, t = rb & (LL - 1);
        int torig = dir ? (LL - 1 - t) : t;
        asrc = A + ((size_t)(b * LL + torig)) * K + k0 + kc * 8;
      } else {
        asrc = A + (size_t)(row0 + rr) * K + k0 + kc * 8;
      }
      const short* bsrc = Wp + (size_t)(col0 + rr) * K + k0 + kc * 8;
      gld16(asrc, &As[(s * 256 + wv * 64) * 8]);   // wave-uniform LDS base
      gld16(bsrc, &Bs[(s * 256 + wv * 64) * 8]);
    }
    __syncthreads();
    bf16x8 af[4], bfr[4];
    const int krow = (lane >> 4) * 8;
#pragma unroll
    for (int m = 0; m < 4; ++m)
      af[m] = *reinterpret_cast<const bf16x8*>(&As[(wrow + m * 16 + (lane & 15)) * 32 + krow]);
#pragma unroll
    for (int n = 0; n < 4; ++n)
      bfr[n] = *reinterpret_cast<const bf16x8*>(&Bs[(wcol + n * 16 + (lane & 15)) * 32 + krow]);
#pragma unroll
    for (int m = 0; m < 4; ++m)
#pragma unroll
      for (int n = 0; n < 4; ++n)
        acc[m][n] = __builtin_amdgcn_mfma_f32_16x16x32_bf16(af[m], bfr[n], acc[m][n], 0, 0, 0);
    __syncthreads();
  }

  // epilogue: C/D layout col=lane&15, row=(lane>>4)*4+reg
#pragma unroll
  for (int m = 0; m < 4; ++m) {
#pragma unroll
    for (int i = 0; i < 4; ++i) {
      int r = row0 + wrow + m * 16 + (lane >> 4) * 4 + i;
      size_t obase;
      if (EP == 1) {
        int rb = r & (BL - 1);
        int b = rb >> 11, t = rb & (LL - 1);
        int torig = dir ? (LL - 1 - t) : t;
        obase = ((size_t)(dir * BB + b) * LL + torig) * DM;
      } else {
        obase = (size_t)r * N;
      }
#pragma unroll
      for (int n = 0; n < 4; ++n) {
        int c = col0 + wcol + n * 16 + (lane & 15);
        float val = acc[m][n][i];
        if (EP == 1) {
          int o = dir * DM + c;
          val = (val - P2[o]) * rsqrtf(P3[o] + EPSV) * P0[o] + P1[o];
          Cf[obase + c] = val;
        } else if (EP == 2) {
          val = fmaxf(val + P0[c], 0.f);
          Ch[obase + c] = f2bf(val);
        } else if (EP == 3) {
          val = val + P0[c];
          int o = 2 * DM + c;
          val = (val - P3[o]) * rsqrtf(P4[o] + EPSV) * P1[o] + P2[o];
          val += P5[obase + c];
          Cf[obase + c] = val;
        } else {
          Cf[obase + c] = val;
        }
      }
    }
  }
}

// ---------------------------------------------------------------------------
// causal depthwise conv (taps=4) + bias + SiLU, float4 over channels.
// ---------------------------------------------------------------------------
__global__ __launch_bounds__(256) void conv_silu_kernel(
    const float* __restrict__ XZ, const float* __restrict__ cw,
    const float* __restrict__ cb, float* __restrict__ XI)
{
  int idx = blockIdx.x * 256 + threadIdx.x;   // [0, 16.7M/4)
  int dq = (idx & 127) * 4;                   // channel group base
  int r  = idx >> 7;                          // (dir*4+b)*2048 + t
  int t  = r & (LL - 1);
  int db = r >> 11;
  int dir = db >> 2;
  size_t base = (size_t)db * LL * 1024 + dq;  // x-half of XZ, t'=0
  float4 wc0 = *reinterpret_cast<const float4*>(cw + (size_t)(dir * DI + dq + 0) * 4);
  float4 wc1 = *reinterpret_cast<const float4*>(cw + (size_t)(dir * DI + dq + 1) * 4);
  float4 wc2 = *reinterpret_cast<const float4*>(cw + (size_t)(dir * DI + dq + 2) * 4);
  float4 wc3 = *reinterpret_cast<const float4*>(cw + (size_t)(dir * DI + dq + 3) * 4);
  float4 bv  = *reinterpret_cast<const float4*>(cb + dir * DI + dq);
  float a0 = bv.x, a1 = bv.y, a2 = bv.z, a3 = bv.w;
#pragma unroll
  for (int j = 0; j < 4; ++j) {
    int tp = t - 3 + j;
    if (tp >= 0) {
      float4 xv = *reinterpret_cast<const float4*>(XZ + base + (size_t)tp * 1024);
      float w0j = j == 0 ? wc0.x : j == 1 ? wc0.y : j == 2 ? wc0.z : wc0.w;
      float w1j = j == 0 ? wc1.x : j == 1 ? wc1.y : j == 2 ? wc1.z : wc1.w;
      float w2j = j == 0 ? wc2.x : j == 1 ? wc2.y : j == 2 ? wc2.z : wc2.w;
      float w3j = j == 0 ? wc3.x : j == 1 ? wc3.y : j == 2 ? wc3.z : wc3.w;
      a0 = fmaf(w0j, xv.x, a0); a1 = fmaf(w1j, xv.y, a1);
      a2 = fmaf(w2j, xv.z, a2); a3 = fmaf(w3j, xv.w, a3);
    }
  }
  float4 o = make_float4(fsilu(a0), fsilu(a1), fsilu(a2), fsilu(a3));
  *reinterpret_cast<float4*>(XI + (size_t)r * DI + dq) = o;
}

// ---------------------------------------------------------------------------
// xproj: DBC(M2 x 48) = XI(M2 x 512) @ xproj_w(dir)^T.  64-row tiles, fp32.
// ---------------------------------------------------------------------------
__global__ __launch_bounds__(256) void xproj_kernel(
    const float* __restrict__ XI, const float* __restrict__ W, float* __restrict__ DBC)
{
  __shared__ __align__(16) float As[64 * 68];   // [k][row]
  __shared__ __align__(16) float Ws[64 * 52];   // [k][col]
  const int tid = threadIdx.x;
  const int row0 = blockIdx.x * 64;
  const int dir = row0 >= BL ? 1 : 0;
  const float* Wp = W + (size_t)dir * 48 * DI;
  const int TX = tid & 15, TY = tid >> 4;
  float acc[4][3];
#pragma unroll
  for (int i = 0; i < 4; ++i)
#pragma unroll
    for (int j = 0; j < 3; ++j) acc[i][j] = 0.f;

  for (int k0 = 0; k0 < DI; k0 += 64) {
#pragma unroll
    for (int s = 0; s < 4; ++s) {
      int f = tid + s * 256;
      int kq = f & 15, m = f >> 4;
      float4 v = *reinterpret_cast<const float4*>(XI + (size_t)(row0 + m) * DI + k0 + kq * 4);
      int kk = kq * 4;
      As[(kk + 0) * 68 + m] = v.x; As[(kk + 1) * 68 + m] = v.y;
      As[(kk + 2) * 68 + m] = v.z; As[(kk + 3) * 68 + m] = v.w;
    }
#pragma unroll
    for (int s = 0; s < 3; ++s) {
      int f = tid + s * 256;
      int kq = f & 15, n = f >> 4;
      float4 v = *reinterpret_cast<const float4*>(Wp + (size_t)n * DI + k0 + kq * 4);
      int kk = kq * 4;
      Ws[(kk + 0) * 52 + n] = v.x; Ws[(kk + 1) * 52 + n] = v.y;
      Ws[(kk + 2) * 52 + n] = v.z; Ws[(kk + 3) * 52 + n] = v.w;
    }
    __syncthreads();
    for (int k = 0; k < 64; ++k) {
      float a[4], b[3];
#pragma unroll
      for (int i = 0; i < 4; ++i) a[i] = As[k * 68 + TY * 4 + i];
#pragma unroll
      for (int j = 0; j < 3; ++j) b[j] = Ws[k * 52 + TX * 3 + j];
#pragma unroll
      for (int i = 0; i < 4; ++i)
#pragma unroll
        for (int j = 0; j < 3; ++j) acc[i][j] = fmaf(a[i], b[j], acc[i][j]);
    }
    __syncthreads();
  }
#pragma unroll
  for (int i = 0; i < 4; ++i)
#pragma unroll
    for (int j = 0; j < 3; ++j)
      DBC[(size_t)(row0 + TY * 4 + i) * 48 + TX * 3 + j] = acc[i][j];
}

// ---------------------------------------------------------------------------
// delta = softplus(dt @ dt_w^T + dt_b); one block per (dir,b,t) row
// ---------------------------------------------------------------------------
__global__ __launch_bounds__(256) void dtproj_kernel(
    const float* __restrict__ DBC, const float* __restrict__ dt_w,
    const float* __restrict__ dt_b, float* __restrict__ DELTA)
{
  int row = blockIdx.x;            // [0, 16384)
  int dir = row >> 13;
  __shared__ float dtv[16];
  if (threadIdx.x < 16) dtv[threadIdx.x] = DBC[(size_t)row * 48 + threadIdx.x];
  __syncthreads();
  for (int dd = threadIdx.x; dd < DI; dd += 256) {
    const float* wrow = dt_w + (size_t)(dir * DI + dd) * 16;
    float a = dt_b[dir * DI + dd];
#pragma unroll
    for (int r = 0; r < 16; ++r) a = fmaf(dtv[r], wrow[r], a);
    float sp = (a > 20.f) ? a : log1pf(__expf(a));
    DELTA[(size_t)row * DI + dd] = sp;
  }
}

// ---------------------------------------------------------------------------
// Chunked scan, 4 states/thread. Block = 64 channels of one (dir,b,chunk).
// thread: d = tid>>2 (0..63), n4 = tid&3 (states n4*4..n4*4+3).
// LDS: D/X transposed [d][t] stride 20; B/C [t][n] stride 16. Double-buffered.
// pass 1: recurrence from h0=0 -> HEND, SDT. grid 960 (15 chunks x 64 groups).
// ---------------------------------------------------------------------------
__global__ __launch_bounds__(256) void scan1_kernel(
    const float* __restrict__ DELTA, const float* __restrict__ XI,
    const float* __restrict__ DBC, const float* __restrict__ Alog,
    float* __restrict__ HEND, float* __restrict__ SDT)
{
  __shared__ __align__(16) float Dl[2][1280], Xl[2][1280], Bl[2][256];
  const int tid = threadIdx.x;
  const int lane = tid & 63, wv = tid >> 6;
  const int d = tid >> 2, n4 = tid & 3;
  const int blk = blockIdx.x & 63, chunk = blockIdx.x >> 6;
  const int chain0 = blk * 64;
  const int dir = chain0 >> 11, b = (chain0 >> 9) & 3;
  const int d0 = chain0 & 511;
  const int gd = d0 + d;

  float4 Av = *reinterpret_cast<const float4*>(Alog + ((size_t)(dir * DI + gd)) * 16 + n4 * 4);
  const float An[4] = {-__expf(Av.x), -__expf(Av.y), -__expf(Av.z), -__expf(Av.w)};
  const size_t seq = (size_t)(dir * BB + b) * LL + chunk * CHL;
  const size_t baseDU = seq * DI;
  const size_t baseBC = seq * 48;

  const int st = lane & 15, sq = lane >> 4;   // stager: t, d-quad-group

  auto stageDX = [&](const float* __restrict__ src, float (*dst)[1280],
                     int w16, int bs, int i) {
    float4 v = *reinterpret_cast<const float4*>(
        src + baseDU + (size_t)(w16 + st) * DI + d0 + i * 16 + sq * 4);
    int dd = i * 16 + sq * 4;
    dst[bs][(dd + 0) * 20 + st] = v.x; dst[bs][(dd + 1) * 20 + st] = v.y;
    dst[bs][(dd + 2) * 20 + st] = v.z; dst[bs][(dd + 3) * 20 + st] = v.w;
  };
  auto stageB = [&](int w16, int bs) {
    int t = lane >> 2, nq = lane & 3;
    float4 v = *reinterpret_cast<const float4*>(
        DBC + baseBC + (size_t)(w16 + t) * 48 + 16 + nq * 4);
    *reinterpret_cast<float4*>(&Bl[bs][t * 16 + nq * 4]) = v;
  };
  auto stage = [&](int w16, int bs) {
    if (wv == 0)      { stageDX(DELTA, Dl, w16, bs, 0); stageDX(DELTA, Dl, w16, bs, 1); }
    else if (wv == 1) { stageDX(DELTA, Dl, w16, bs, 2); stageDX(DELTA, Dl, w16, bs, 3); }
    else if (wv == 2) { stageDX(XI, Xl, w16, bs, 0); stageDX(XI, Xl, w16, bs, 1); }
    else              { stageDX(XI, Xl, w16, bs, 2); stageDX(XI, Xl, w16, bs, 3); stageB(w16, bs); }
  };

  float h[4] = {0.f, 0.f, 0.f, 0.f};
  float sdt = 0.f;
  stage(0, 0);
  __syncthreads();

  for (int w = 0; w < CHL / 16; ++w) {
    const int bb = w & 1;
    float rdt[16], ru[16];
#pragma unroll
    for (int q = 0; q < 4; ++q) {
      *reinterpret_cast<float4*>(&rdt[4 * q]) = *reinterpret_cast<const float4*>(&Dl[bb][d * 20 + 4 * q]);
      *reinterpret_cast<float4*>(&ru[4 * q])  = *reinterpret_cast<const float4*>(&Xl[bb][d * 20 + 4 * q]);
    }
    if (w + 1 < CHL / 16) stage((w + 1) * 16, bb ^ 1);
#pragma unroll
    for (int tt = 0; tt < 16; ++tt) {
      float4 rB = *reinterpret_cast<const float4*>(&Bl[bb][tt * 16 + n4 * 4]);
      float du = rdt[tt] * ru[tt];
      float bv[4] = {rB.x, rB.y, rB.z, rB.w};
#pragma unroll
      for (int s = 0; s < 4; ++s) {
        float dA = __expf(rdt[tt] * An[s]);
        h[s] = fmaf(dA, h[s], du * bv[s]);
      }
      sdt += rdt[tt];
    }
    __syncthreads();
  }
  *reinterpret_cast<float4*>(&HEND[((size_t)chunk * NCHAIN + chain0 + d) * 16 + n4 * 4]) =
      make_float4(h[0], h[1], h[2], h[3]);
  if (n4 == 0) SDT[chunk * NCHAIN + chain0 + d] = sdt;
}

// ---------------------------------------------------------------------------
// pass 2: scan across chunks per chain. grid: 256 blocks.
// ---------------------------------------------------------------------------
__global__ __launch_bounds__(256) void scan2_kernel(
    const float* __restrict__ HEND, const float* __restrict__ SDT,
    const float* __restrict__ Alog, float* __restrict__ HINIT)
{
  const int tid = threadIdx.x;
  const int cl = tid >> 4, n = tid & 15;
  const int chain = blockIdx.x * 16 + cl;
  const int dir = chain >> 11;
  const int d   = chain & 511;
  const float An = -__expf(Alog[((size_t)(dir * DI + d)) * 16 + n]);
  float h = 0.f;
#pragma unroll
  for (int c = 0; c < NCH; ++c) {
    size_t o = ((size_t)c * NCHAIN + chain) * 16 + n;
    HINIT[o] = h;
    float ap = __expf(An * SDT[c * NCHAIN + chain]);
    h = fmaf(ap, h, HEND[o]);
  }
}

// ---------------------------------------------------------------------------
// pass 3: recurrence from HINIT + DPP quad-reduce + fused gate -> G16 bf16.
// grid 1024 (16 chunks x 64 groups).
// ---------------------------------------------------------------------------
__global__ __launch_bounds__(256) void scan3_kernel(
    const float* __restrict__ DELTA, const float* __restrict__ XI,
    const float* __restrict__ DBC, const float* __restrict__ Alog,
    const float* __restrict__ HINIT, const float* __restrict__ XZ,
    const float* __restrict__ Dp, short* __restrict__ G16)
{
  __shared__ __align__(16) float Dl[2][1280], Xl[2][1280], Bl[2][256], Cl[2][256];
  const int tid = threadIdx.x;
  const int lane = tid & 63, wv = tid >> 6;
  const int d = tid >> 2, n4 = tid & 3;
  const int blk = blockIdx.x & 63, chunk = blockIdx.x >> 6;
  const int chain0 = blk * 64;
  const int dir = chain0 >> 11, b = (chain0 >> 9) & 3;
  const int d0 = chain0 & 511;
  const int gd = d0 + d;

  float4 Av = *reinterpret_cast<const float4*>(Alog + ((size_t)(dir * DI + gd)) * 16 + n4 * 4);
  const float An[4] = {-__expf(Av.x), -__expf(Av.y), -__expf(Av.z), -__expf(Av.w)};
  const size_t seq = (size_t)(dir * BB + b) * LL + chunk * CHL;
  const size_t baseDU = seq * DI;
  const size_t baseBC = seq * 48;
  const float Dskip = Dp[dir * DI + gd];

  float4 hi = *reinterpret_cast<const float4*>(
      &HINIT[((size_t)chunk * NCHAIN + chain0 + d) * 16 + n4 * 4]);
  float h[4] = {hi.x, hi.y, hi.z, hi.w};

  const int st = lane & 15, sq = lane >> 4;

  auto stageDX = [&](const float* __restrict__ src, float (*dst)[1280],
                     int w16, int bs, int i) {
    float4 v = *reinterpret_cast<const float4*>(
        src + baseDU + (size_t)(w16 + st) * DI + d0 + i * 16 + sq * 4);
    int dd = i * 16 + sq * 4;
    dst[bs][(dd + 0) * 20 + st] = v.x; dst[bs][(dd + 1) * 20 + st] = v.y;
    dst[bs][(dd + 2) * 20 + st] = v.z; dst[bs][(dd + 3) * 20 + st] = v.w;
  };
  auto stageBC = [&](float (*dst)[256], int off, int w16, int bs) {
    int t = lane >> 2, nq = lane & 3;
    float4 v = *reinterpret_cast<const float4*>(
        DBC + baseBC + (size_t)(w16 + t) * 48 + off + nq * 4);
    *reinterpret_cast<float4*>(&dst[bs][t * 16 + nq * 4]) = v;
  };
  auto stage = [&](int w16, int bs) {
    if (wv == 0)      { stageDX(DELTA, Dl, w16, bs, 0); stageDX(DELTA, Dl, w16, bs, 1); }
    else if (wv == 1) { stageDX(DELTA, Dl, w16, bs, 2); stageDX(DELTA, Dl, w16, bs, 3); }
    else if (wv == 2) { stageDX(XI, Xl, w16, bs, 0); stageDX(XI, Xl, w16, bs, 1); stageBC(Bl, 16, w16, bs); }
    else              { stageDX(XI, Xl, w16, bs, 2); stageDX(XI, Xl, w16, bs, 3); stageBC(Cl, 32, w16, bs); }
  };

  stage(0, 0);
  __syncthreads();

  for (int w = 0; w < CHL / 16; ++w) {
    const int bb = w & 1;
    float rdt[16], ru[16];
#pragma unroll
    for (int q = 0; q < 4; ++q) {
      *reinterpret_cast<float4*>(&rdt[4 * q]) = *reinterpret_cast<const float4*>(&Dl[bb][d * 20 + 4 * q]);
      *reinterpret_cast<float4*>(&ru[4 * q])  = *reinterpret_cast<const float4*>(&Xl[bb][d * 20 + 4 * q]);
    }
    if (w + 1 < CHL / 16) stage((w + 1) * 16, bb ^ 1);
    // direct z loads for this thread's 4 output timesteps (t = n4*4 + j)
    float zq[4];
#pragma unroll
    for (int j = 0; j < 4; ++j)
      zq[j] = XZ[(seq + w * 16 + n4 * 4 + j) * 1024 + 512 + gd];

    float yq[4] = {0.f, 0.f, 0.f, 0.f}, uq[4] = {0.f, 0.f, 0.f, 0.f};
#pragma unroll
    for (int tt = 0; tt < 16; ++tt) {
      float4 rB = *reinterpret_cast<const float4*>(&Bl[bb][tt * 16 + n4 * 4]);
      float4 rC = *reinterpret_cast<const float4*>(&Cl[bb][tt * 16 + n4 * 4]);
      float du = rdt[tt] * ru[tt];
      float bv[4] = {rB.x, rB.y, rB.z, rB.w};
      float cv[4] = {rC.x, rC.y, rC.z, rC.w};
      float p = 0.f;
#pragma unroll
      for (int s = 0; s < 4; ++s) {
        float dA = __expf(rdt[tt] * An[s]);
        h[s] = fmaf(dA, h[s], du * bv[s]);
        p = fmaf(h[s], cv[s], p);
      }
      p = quad_sum(p);                      // full 16-state sum, all 4 lanes
      bool mine = (tt >> 2) == n4;
      yq[tt & 3] = mine ? p : yq[tt & 3];
      uq[tt & 3] = mine ? ru[tt] : uq[tt & 3];
    }
#pragma unroll
    for (int j = 0; j < 4; ++j) {
      float yy = (yq[j] + uq[j] * Dskip) * fsilu(zq[j]);
      G16[baseDU + (size_t)(w * 16 + n4 * 4 + j) * DI + gd] = f2bf(yy);
    }
    __syncthreads();
  }
}

// ---------------------------------------------------------------------------
// dual AddNorm combine: S16 = bf16(LN0(x+f) + LN1(x+bwd)). one block per (b,t).
// ---------------------------------------------------------------------------
__global__ __launch_bounds__(256) void ln_combine_kernel(
    const float* __restrict__ MOUT, const float* __restrict__ x,
    const float* __restrict__ ln_g, const float* __restrict__ ln_b,
    short* __restrict__ S16)
{
  int row = blockIdx.x;
  int m = threadIdx.x;
  size_t i0 = (size_t)row * DM + m;
  float xv = x[i0];
  float s1 = xv + MOUT[i0];
  float s2 = xv + MOUT[(size_t)BL * DM + i0];
  float a1 = s1, q1 = s1 * s1, a2 = s2, q2 = s2 * s2;
  for (int off = 32; off; off >>= 1) {
    a1 += __shfl_xor(a1, off); q1 += __shfl_xor(q1, off);
    a2 += __shfl_xor(a2, off); q2 += __shfl_xor(q2, off);
  }
  __shared__ float red[4][4];
  int w = m >> 6;
  if ((m & 63) == 0) { red[w][0] = a1; red[w][1] = q1; red[w][2] = a2; red[w][3] = q2; }
  __syncthreads();
  a1 = red[0][0] + red[1][0] + red[2][0] + red[3][0];
  q1 = red[0][1] + red[1][1] + red[2][1] + red[3][1];
  a2 = red[0][2] + red[1][2] + red[2][2] + red[3][2];
  q2 = red[0][3] + red[1][3] + red[2][3] + red[3][3];
  const float inv = 1.f / 256.f;
  float mu1 = a1 * inv, mu2 = a2 * inv;
  float v1 = q1 * inv - mu1 * mu1, v2 = q2 * inv - mu2 * mu2;
  float r1 = rsqrtf(v1 + EPSV), r2 = rsqrtf(v2 + EPSV);
  float out = (s1 - mu1) * r1 * ln_g[m] + ln_b[m] +
              (s2 - mu2) * r2 * ln_g[DM + m] + ln_b[DM + m];
  S16[i0] = f2bf(out);
}

}  // namespace

// ---------------------------------------------------------------------------
// workspace (floats):
//   XZ    @ 0          16,777,216  (2,B,L,1024)  [bf16 H16 after scan3]
//   XI    @ 16777216    8,388,608  (2,B,L,512)   [fp32 MOUT after out_proj]
//   DBC   @ 25165824      786,432  (2,B,L,48)
//   DELTA @ 25952256    8,388,608  (2,B,L,512)
//   YS    @ 34340864    8,388,608  [bf16 G16 from scan3; later bf16 S16]
//   X16   @ 42729472    1,048,576  (bf16 x)
//   W16   @ 43778048      655,360  (bf16 weights)
//   HEND  @ 44433408    1,048,576  (16,4096,16)
//   HINIT @ 45481984    1,048,576  (16,4096,16)
//   SDT   @ 46530560       65,536  (16,4096)
// total 46,596,096 floats = 186.4 MB
// ---------------------------------------------------------------------------
extern "C" void kernel_launch(void* const* d_in, const int* in_sizes, int n_in,
                              void* d_out, int out_size, void* d_ws, size_t ws_size,
                              hipStream_t stream) {
  (void)in_sizes; (void)n_in; (void)out_size; (void)ws_size;
  const float* x      = (const float*)d_in[0];
  const float* in_w   = (const float*)d_in[1];
  const float* conv_w = (const float*)d_in[2];
  const float* conv_b = (const float*)d_in[3];
  const float* xproj_w= (const float*)d_in[4];
  const float* dt_w   = (const float*)d_in[5];
  const float* dt_b   = (const float*)d_in[6];
  const float* Alog   = (const float*)d_in[7];
  const float* Dp     = (const float*)d_in[8];
  const float* out_w  = (const float*)d_in[9];
  const float* bn_g   = (const float*)d_in[10];
  const float* bn_b   = (const float*)d_in[11];
  const float* bn_m   = (const float*)d_in[12];
  const float* bn_v   = (const float*)d_in[13];
  const float* ln_g   = (const float*)d_in[14];
  const float* ln_b   = (const float*)d_in[15];
  const float* w1     = (const float*)d_in[16];
  const float* b1     = (const float*)d_in[17];
  const float* w2     = (const float*)d_in[18];
  const float* b2     = (const float*)d_in[19];

  float* ws    = (float*)d_ws;
  float* XZ    = ws;
  float* XI    = ws + 16777216;
  float* DBC   = ws + 25165824;
  float* DELTA = ws + 25952256;
  float* YS    = ws + 34340864;
  short* X16   = (short*)(ws + 42729472);
  short* W16   = (short*)(ws + 43778048);
  short* IN16  = W16;
  short* OUT16 = W16 + 524288;
  short* W1_16 = W16 + 786432;
  short* W2_16 = W16 + 1048576;
  float* HEND  = ws + 44433408;
  float* HINIT = ws + 45481984;
  float* SDT   = ws + 46530560;
  short* G16   = (short*)YS;          // scan3 output (YS region)
  float* MOUT  = XI;                  // XI dead after scan3
  short* S16   = (short*)YS;          // G16 dead after out_proj
  short* H16   = (short*)XZ;          // XZ dead after scan3
  float* OUT   = (float*)d_out;

  dim3 blk(256);

  // 0. bf16 conversions (x + 4 weight tensors, single launch)
  cvt5_kernel<<<3328, blk, 0, stream>>>(x, in_w, out_w, w1, w2,
      X16, IN16, OUT16, W1_16, W2_16);

  // 1. in_proj (both dirs, flip via row map) -> XZ fp32
  mgemm<0><<<dim3(8, 128), blk, 0, stream>>>(X16, IN16, XZ, nullptr, 1024, 256,
      nullptr, nullptr, nullptr, nullptr, nullptr, nullptr);
  // 2. depthwise conv + SiLU -> XI (float4)
  conv_silu_kernel<<<16384, blk, 0, stream>>>(XZ, conv_w, conv_b, XI);
  // 3. x_proj -> DBC
  xproj_kernel<<<256, blk, 0, stream>>>(XI, xproj_w, DBC);
  // 4. dt proj + softplus -> DELTA
  dtproj_kernel<<<16384, blk, 0, stream>>>(DBC, dt_w, dt_b, DELTA);
  // 5. chunked SSM scan (4 states/thread), gate fused into pass 3 -> G16
  scan1_kernel<<<960,  blk, 0, stream>>>(DELTA, XI, DBC, Alog, HEND, SDT);
  scan2_kernel<<<256,  blk, 0, stream>>>(HEND, SDT, Alog, HINIT);
  scan3_kernel<<<1024, blk, 0, stream>>>(DELTA, XI, DBC, Alog, HINIT, XZ, Dp, G16);
  // 7. out_proj + BN(dir) + un-flip -> MOUT (fp32, overwrites XI)
  mgemm<1><<<dim3(2, 128), blk, 0, stream>>>(G16, OUT16, MOUT, nullptr, 256, 512,
      bn_g, bn_b, bn_m, bn_v, nullptr, nullptr);
  // 8. dual AddNorm combine -> S16 (bf16, overwrites G16 region)
  ln_combine_kernel<<<8192, blk, 0, stream>>>(MOUT, x, ln_g, ln_b, S16);
  // 9. FF1 (+bias, ReLU) -> H16 (bf16, overwrites XZ)
  mgemm<2><<<dim3(8, 64), blk, 0, stream>>>(S16, W1_16, nullptr, H16, 1024, 256,
      b1, nullptr, nullptr, nullptr, nullptr, nullptr);
  // 10. FF2 (+bias, BN[2], +x) -> OUT fp32
  mgemm<3><<<dim3(2, 64), blk, 0, stream>>>(H16, W2_16, OUT, nullptr, 256, 1024,
      b2, bn_g, bn_b, bn_m, bn_v, x);
}

// Round 7
// 274.421 us; speedup vs baseline: 1.3038x; 1.1582x over previous
//
#include <hip/hip_runtime.h>
#include <hip/hip_bf16.h>
#include <cstdint>
#include <cstddef>

namespace {

constexpr int BB  = 4;      // batch
constexpr int LL  = 2048;   // seq
constexpr int DM  = 256;    // d_model
constexpr int DI  = 512;    // d_inner
constexpr int DFF = 1024;
constexpr float EPSV = 1e-5f;
constexpr int BL  = BB * LL;     // 8192 rows per direction
constexpr int M2  = 2 * BL;      // 16384 rows (both dirs)
constexpr int NCH = 16;          // scan chunks
constexpr int CHL = LL / NCH;    // 128 timesteps per chunk
constexpr int NCHAIN = 2 * BB * DI;   // 4096 scan chains

typedef __attribute__((ext_vector_type(8))) short bf16x8;
typedef __attribute__((ext_vector_type(4))) float f32x4;

__device__ __forceinline__ float fsilu(float v) { return v / (1.f + __expf(-v)); }

__device__ __forceinline__ short f2bf(float f) {
  union { float f; uint32_t u; } v; v.f = f;
  uint32_t r = (v.u + 0x7fffu + ((v.u >> 16) & 1u)) >> 16;
  return (short)r;
}

__device__ __forceinline__ void gld16(const short* g, short* l) {
  __builtin_amdgcn_global_load_lds(
      (const __attribute__((address_space(1))) void*)g,
      (__attribute__((address_space(3))) void*)l, 16, 0, 0);
}

// quad (4-lane) sum via DPP quad_perm — pure VALU, no LDS traffic
__device__ __forceinline__ float quad_sum(float v) {
  int a = __builtin_amdgcn_update_dpp(0, __float_as_int(v), 0xB1, 0xF, 0xF, true); // xor1
  v += __int_as_float(a);
  int b = __builtin_amdgcn_update_dpp(0, __float_as_int(v), 0x4E, 0xF, 0xF, true); // xor2
  v += __int_as_float(b);
  return v;
}

// ---------------------------------------------------------------------------
// fused f32 -> bf16 convert for x + 4 weight tensors (one launch)
// ---------------------------------------------------------------------------
__global__ __launch_bounds__(256) void cvt5_kernel(
    const float* __restrict__ s0, const float* __restrict__ s1,
    const float* __restrict__ s2, const float* __restrict__ s3,
    const float* __restrict__ s4,
    short* __restrict__ o0, short* __restrict__ o1, short* __restrict__ o2,
    short* __restrict__ o3, short* __restrict__ o4)
{
  int bid = blockIdx.x;
  const float* s; short* o; int i;
  if (bid < 2048)      { s = s0; o = o0; i = bid; }
  else if (bid < 2560) { s = s1; o = o1; i = bid - 2048; }
  else if (bid < 2816) { s = s2; o = o2; i = bid - 2560; }
  else if (bid < 3072) { s = s3; o = o3; i = bid - 2816; }
  else                 { s = s4; o = o4; i = bid - 3072; }
  int off = (i * 256 + threadIdx.x) * 4;
  float4 v = *reinterpret_cast<const float4*>(s + off);
  ushort4 u;
  u.x = (unsigned short)f2bf(v.x); u.y = (unsigned short)f2bf(v.y);
  u.z = (unsigned short)f2bf(v.z); u.w = (unsigned short)f2bf(v.w);
  *reinterpret_cast<ushort4*>(o + off) = u;
}

// ---------------------------------------------------------------------------
// bf16 MFMA GEMM, 128x128 tile, BK=32, 4 waves of 64x64, fp32 accum.
// ---------------------------------------------------------------------------
template <int EP>
__global__ __launch_bounds__(256) void mgemm(
    const short* __restrict__ A, const short* __restrict__ W,
    float* __restrict__ Cf, short* __restrict__ Ch, int N, int K,
    const float* __restrict__ P0, const float* __restrict__ P1,
    const float* __restrict__ P2, const float* __restrict__ P3,
    const float* __restrict__ P4, const float* __restrict__ P5)
{
  __shared__ short As[128 * 32];
  __shared__ short Bs[128 * 32];
  const int tid  = threadIdx.x;
  const int lane = tid & 63, wv = tid >> 6;
  const int wrow = (wv >> 1) * 64, wcol = (wv & 1) * 64;
  const int row0 = blockIdx.y * 128, col0 = blockIdx.x * 128;
  const int dir  = (EP == 0 || EP == 1) ? (row0 >= BL ? 1 : 0) : 0;
  const short* Wp = W + (size_t)dir * (size_t)N * (size_t)K;

  f32x4 acc[4][4];
#pragma unroll
  for (int m = 0; m < 4; ++m)
#pragma unroll
    for (int n = 0; n < 4; ++n) acc[m][n] = (f32x4){0.f, 0.f, 0.f, 0.f};

  for (int k0 = 0; k0 < K; k0 += 32) {
#pragma unroll
    for (int s = 0; s < 2; ++s) {
      int f = s * 256 + wv * 64 + lane;      // [0,512)
      int rr = f >> 2, kc = f & 3;           // tile row, 16B chunk along k
      const short* asrc;
      if (EP == 0) {
        int r  = row0 + rr;
        int rb = r & (BL - 1);
        int b = rb >> 11, t = rb & (LL - 1);
        int torig = dir ? (LL - 1 - t) : t;
        asrc = A + ((size_t)(b * LL + torig)) * K + k0 + kc * 8;
      } else {
        asrc = A + (size_t)(row0 + rr) * K + k0 + kc * 8;
      }
      const short* bsrc = Wp + (size_t)(col0 + rr) * K + k0 + kc * 8;
      gld16(asrc, &As[(s * 256 + wv * 64) * 8]);   // wave-uniform LDS base
      gld16(bsrc, &Bs[(s * 256 + wv * 64) * 8]);
    }
    __syncthreads();
    bf16x8 af[4], bfr[4];
    const int krow = (lane >> 4) * 8;
#pragma unroll
    for (int m = 0; m < 4; ++m)
      af[m] = *reinterpret_cast<const bf16x8*>(&As[(wrow + m * 16 + (lane & 15)) * 32 + krow]);
#pragma unroll
    for (int n = 0; n < 4; ++n)
      bfr[n] = *reinterpret_cast<const bf16x8*>(&Bs[(wcol + n * 16 + (lane & 15)) * 32 + krow]);
#pragma unroll
    for (int m = 0; m < 4; ++m)
#pragma unroll
      for (int n = 0; n < 4; ++n)
        acc[m][n] = __builtin_amdgcn_mfma_f32_16x16x32_bf16(af[m], bfr[n], acc[m][n], 0, 0, 0);
    __syncthreads();
  }

  // epilogue: C/D layout col=lane&15, row=(lane>>4)*4+reg
#pragma unroll
  for (int m = 0; m < 4; ++m) {
#pragma unroll
    for (int i = 0; i < 4; ++i) {
      int r = row0 + wrow + m * 16 + (lane >> 4) * 4 + i;
      size_t obase;
      if (EP == 1) {
        int rb = r & (BL - 1);
        int b = rb >> 11, t = rb & (LL - 1);
        int torig = dir ? (LL - 1 - t) : t;
        obase = ((size_t)(dir * BB + b) * LL + torig) * DM;
      } else {
        obase = (size_t)r * N;
      }
#pragma unroll
      for (int n = 0; n < 4; ++n) {
        int c = col0 + wcol + n * 16 + (lane & 15);
        float val = acc[m][n][i];
        if (EP == 1) {
          int o = dir * DM + c;
          val = (val - P2[o]) * rsqrtf(P3[o] + EPSV) * P0[o] + P1[o];
          Cf[obase + c] = val;
        } else if (EP == 2) {
          val = fmaxf(val + P0[c], 0.f);
          Ch[obase + c] = f2bf(val);
        } else if (EP == 3) {
          val = val + P0[c];
          int o = 2 * DM + c;
          val = (val - P3[o]) * rsqrtf(P4[o] + EPSV) * P1[o] + P2[o];
          val += P5[obase + c];
          Cf[obase + c] = val;
        } else {
          Cf[obase + c] = val;
        }
      }
    }
  }
}

// ---------------------------------------------------------------------------
// causal depthwise conv (taps=4) + bias + SiLU.
// Register rolling window: thread = (channel-quad, 8 consecutive t).
// Block = (db, 16-t tile): streams a contiguous 16x512 slab.
// grid 1024 = 8 db x 128 t-tiles.
// ---------------------------------------------------------------------------
__global__ __launch_bounds__(256) void conv_silu_kernel(
    const float* __restrict__ XZ, const float* __restrict__ cw,
    const float* __restrict__ cb, float* __restrict__ XI)
{
  const int bid = blockIdx.x;
  const int db = bid >> 7, tb = bid & 127;     // db = dir*4+b
  const int dir = db >> 2;
  const int tid = threadIdx.x;
  const int dq = (tid & 127) * 4;              // channel quad base
  const int t0 = tb * 16 + (tid >> 7) * 8;     // 8 timesteps per thread
  const size_t base = (size_t)db * LL * 1024 + dq;   // x-half of XZ

  float4 wc0 = *reinterpret_cast<const float4*>(cw + (size_t)(dir * DI + dq + 0) * 4);
  float4 wc1 = *reinterpret_cast<const float4*>(cw + (size_t)(dir * DI + dq + 1) * 4);
  float4 wc2 = *reinterpret_cast<const float4*>(cw + (size_t)(dir * DI + dq + 2) * 4);
  float4 wc3 = *reinterpret_cast<const float4*>(cw + (size_t)(dir * DI + dq + 3) * 4);
  float4 bv  = *reinterpret_cast<const float4*>(cb + dir * DI + dq);

  auto ld = [&](int t) -> float4 {
    if (t < 0) return make_float4(0.f, 0.f, 0.f, 0.f);   // causal zero-pad
    return *reinterpret_cast<const float4*>(XZ + base + (size_t)t * 1024);
  };

  float4 h0 = ld(t0 - 3), h1 = ld(t0 - 2), h2 = ld(t0 - 1);
#pragma unroll
  for (int j = 0; j < 8; ++j) {
    const int t = t0 + j;
    float4 h3 = ld(t);
    float4 o;
    o.x = fsilu(bv.x + wc0.x * h0.x + wc0.y * h1.x + wc0.z * h2.x + wc0.w * h3.x);
    o.y = fsilu(bv.y + wc1.x * h0.y + wc1.y * h1.y + wc1.z * h2.y + wc1.w * h3.y);
    o.z = fsilu(bv.z + wc2.x * h0.z + wc2.y * h1.z + wc2.z * h2.z + wc2.w * h3.z);
    o.w = fsilu(bv.w + wc3.x * h0.w + wc3.y * h1.w + wc3.z * h2.w + wc3.w * h3.w);
    *reinterpret_cast<float4*>(XI + ((size_t)db * LL + t) * DI + dq) = o;
    h0 = h1; h1 = h2; h2 = h3;
  }
}

// ---------------------------------------------------------------------------
// xproj: DBC(M2 x 48) = XI(M2 x 512) @ xproj_w(dir)^T.  64-row tiles, fp32.
// ---------------------------------------------------------------------------
__global__ __launch_bounds__(256) void xproj_kernel(
    const float* __restrict__ XI, const float* __restrict__ W, float* __restrict__ DBC)
{
  __shared__ __align__(16) float As[64 * 68];   // [k][row]
  __shared__ __align__(16) float Ws[64 * 52];   // [k][col]
  const int tid = threadIdx.x;
  const int row0 = blockIdx.x * 64;
  const int dir = row0 >= BL ? 1 : 0;
  const float* Wp = W + (size_t)dir * 48 * DI;
  const int TX = tid & 15, TY = tid >> 4;
  float acc[4][3];
#pragma unroll
  for (int i = 0; i < 4; ++i)
#pragma unroll
    for (int j = 0; j < 3; ++j) acc[i][j] = 0.f;

  for (int k0 = 0; k0 < DI; k0 += 64) {
#pragma unroll
    for (int s = 0; s < 4; ++s) {
      int f = tid + s * 256;
      int kq = f & 15, m = f >> 4;
      float4 v = *reinterpret_cast<const float4*>(XI + (size_t)(row0 + m) * DI + k0 + kq * 4);
      int kk = kq * 4;
      As[(kk + 0) * 68 + m] = v.x; As[(kk + 1) * 68 + m] = v.y;
      As[(kk + 2) * 68 + m] = v.z; As[(kk + 3) * 68 + m] = v.w;
    }
#pragma unroll
    for (int s = 0; s < 3; ++s) {
      int f = tid + s * 256;
      int kq = f & 15, n = f >> 4;
      float4 v = *reinterpret_cast<const float4*>(Wp + (size_t)n * DI + k0 + kq * 4);
      int kk = kq * 4;
      Ws[(kk + 0) * 52 + n] = v.x; Ws[(kk + 1) * 52 + n] = v.y;
      Ws[(kk + 2) * 52 + n] = v.z; Ws[(kk + 3) * 52 + n] = v.w;
    }
    __syncthreads();
    for (int k = 0; k < 64; ++k) {
      float a[4], b[3];
#pragma unroll
      for (int i = 0; i < 4; ++i) a[i] = As[k * 68 + TY * 4 + i];
#pragma unroll
      for (int j = 0; j < 3; ++j) b[j] = Ws[k * 52 + TX * 3 + j];
#pragma unroll
      for (int i = 0; i < 4; ++i)
#pragma unroll
        for (int j = 0; j < 3; ++j) acc[i][j] = fmaf(a[i], b[j], acc[i][j]);
    }
    __syncthreads();
  }
#pragma unroll
  for (int i = 0; i < 4; ++i)
#pragma unroll
    for (int j = 0; j < 3; ++j)
      DBC[(size_t)(row0 + TY * 4 + i) * 48 + TX * 3 + j] = acc[i][j];
}

// ---------------------------------------------------------------------------
// delta = softplus(dt @ dt_w^T + dt_b); one block per (dir,b,t) row
// ---------------------------------------------------------------------------
__global__ __launch_bounds__(256) void dtproj_kernel(
    const float* __restrict__ DBC, const float* __restrict__ dt_w,
    const float* __restrict__ dt_b, float* __restrict__ DELTA)
{
  int row = blockIdx.x;            // [0, 16384)
  int dir = row >> 13;
  __shared__ float dtv[16];
  if (threadIdx.x < 16) dtv[threadIdx.x] = DBC[(size_t)row * 48 + threadIdx.x];
  __syncthreads();
  for (int dd = threadIdx.x; dd < DI; dd += 256) {
    const float* wrow = dt_w + (size_t)(dir * DI + dd) * 16;
    float a = dt_b[dir * DI + dd];
#pragma unroll
    for (int r = 0; r < 16; ++r) a = fmaf(dtv[r], wrow[r], a);
    float sp = (a > 20.f) ? a : log1pf(__expf(a));
    DELTA[(size_t)row * DI + dd] = sp;
  }
}

// ---------------------------------------------------------------------------
// Chunked scan, 4 states/thread. Block = 64 channels of one (dir,b,chunk).
// thread: d = tid>>2 (0..63), n4 = tid&3 (states n4*4..n4*4+3).
// LDS: D/X transposed [d][t] stride 20; B/C [t][n] stride 16. Double-buffered.
// pass 1: recurrence from h0=0 -> HEND, SDT. grid 960 (15 chunks x 64 groups).
// ---------------------------------------------------------------------------
__global__ __launch_bounds__(256) void scan1_kernel(
    const float* __restrict__ DELTA, const float* __restrict__ XI,
    const float* __restrict__ DBC, const float* __restrict__ Alog,
    float* __restrict__ HEND, float* __restrict__ SDT)
{
  __shared__ __align__(16) float Dl[2][1280], Xl[2][1280], Bl[2][256];
  const int tid = threadIdx.x;
  const int lane = tid & 63, wv = tid >> 6;
  const int d = tid >> 2, n4 = tid & 3;
  const int blk = blockIdx.x & 63, chunk = blockIdx.x >> 6;
  const int chain0 = blk * 64;
  const int dir = chain0 >> 11, b = (chain0 >> 9) & 3;
  const int d0 = chain0 & 511;
  const int gd = d0 + d;

  float4 Av = *reinterpret_cast<const float4*>(Alog + ((size_t)(dir * DI + gd)) * 16 + n4 * 4);
  const float An[4] = {-__expf(Av.x), -__expf(Av.y), -__expf(Av.z), -__expf(Av.w)};
  const size_t seq = (size_t)(dir * BB + b) * LL + chunk * CHL;
  const size_t baseDU = seq * DI;
  const size_t baseBC = seq * 48;

  const int st = lane & 15, sq = lane >> 4;   // stager: t, d-quad-group

  auto stageDX = [&](const float* __restrict__ src, float (*dst)[1280],
                     int w16, int bs, int i) {
    float4 v = *reinterpret_cast<const float4*>(
        src + baseDU + (size_t)(w16 + st) * DI + d0 + i * 16 + sq * 4);
    int dd = i * 16 + sq * 4;
    dst[bs][(dd + 0) * 20 + st] = v.x; dst[bs][(dd + 1) * 20 + st] = v.y;
    dst[bs][(dd + 2) * 20 + st] = v.z; dst[bs][(dd + 3) * 20 + st] = v.w;
  };
  auto stageB = [&](int w16, int bs) {
    int t = lane >> 2, nq = lane & 3;
    float4 v = *reinterpret_cast<const float4*>(
        DBC + baseBC + (size_t)(w16 + t) * 48 + 16 + nq * 4);
    *reinterpret_cast<float4*>(&Bl[bs][t * 16 + nq * 4]) = v;
  };
  auto stage = [&](int w16, int bs) {
    if (wv == 0)      { stageDX(DELTA, Dl, w16, bs, 0); stageDX(DELTA, Dl, w16, bs, 1); }
    else if (wv == 1) { stageDX(DELTA, Dl, w16, bs, 2); stageDX(DELTA, Dl, w16, bs, 3); }
    else if (wv == 2) { stageDX(XI, Xl, w16, bs, 0); stageDX(XI, Xl, w16, bs, 1); }
    else              { stageDX(XI, Xl, w16, bs, 2); stageDX(XI, Xl, w16, bs, 3); stageB(w16, bs); }
  };

  float h[4] = {0.f, 0.f, 0.f, 0.f};
  float sdt = 0.f;
  stage(0, 0);
  __syncthreads();

  for (int w = 0; w < CHL / 16; ++w) {
    const int bb = w & 1;
    float rdt[16], ru[16];
#pragma unroll
    for (int q = 0; q < 4; ++q) {
      *reinterpret_cast<float4*>(&rdt[4 * q]) = *reinterpret_cast<const float4*>(&Dl[bb][d * 20 + 4 * q]);
      *reinterpret_cast<float4*>(&ru[4 * q])  = *reinterpret_cast<const float4*>(&Xl[bb][d * 20 + 4 * q]);
    }
    if (w + 1 < CHL / 16) stage((w + 1) * 16, bb ^ 1);
#pragma unroll
    for (int tt = 0; tt < 16; ++tt) {
      float4 rB = *reinterpret_cast<const float4*>(&Bl[bb][tt * 16 + n4 * 4]);
      float du = rdt[tt] * ru[tt];
      float bv[4] = {rB.x, rB.y, rB.z, rB.w};
#pragma unroll
      for (int s = 0; s < 4; ++s) {
        float dA = __expf(rdt[tt] * An[s]);
        h[s] = fmaf(dA, h[s], du * bv[s]);
      }
      sdt += rdt[tt];
    }
    __syncthreads();
  }
  *reinterpret_cast<float4*>(&HEND[((size_t)chunk * NCHAIN + chain0 + d) * 16 + n4 * 4]) =
      make_float4(h[0], h[1], h[2], h[3]);
  if (n4 == 0) SDT[chunk * NCHAIN + chain0 + d] = sdt;
}

// ---------------------------------------------------------------------------
// pass 2: scan across chunks per chain. grid: 256 blocks.
// ---------------------------------------------------------------------------
__global__ __launch_bounds__(256) void scan2_kernel(
    const float* __restrict__ HEND, const float* __restrict__ SDT,
    const float* __restrict__ Alog, float* __restrict__ HINIT)
{
  const int tid = threadIdx.x;
  const int cl = tid >> 4, n = tid & 15;
  const int chain = blockIdx.x * 16 + cl;
  const int dir = chain >> 11;
  const int d   = chain & 511;
  const float An = -__expf(Alog[((size_t)(dir * DI + d)) * 16 + n]);
  float h = 0.f;
#pragma unroll
  for (int c = 0; c < NCH; ++c) {
    size_t o = ((size_t)c * NCHAIN + chain) * 16 + n;
    HINIT[o] = h;
    float ap = __expf(An * SDT[c * NCHAIN + chain]);
    h = fmaf(ap, h, HEND[o]);
  }
}

// ---------------------------------------------------------------------------
// pass 3: recurrence from HINIT + DPP quad-reduce + fused gate -> G16 bf16.
// grid 1024 (16 chunks x 64 groups).
// ---------------------------------------------------------------------------
__global__ __launch_bounds__(256) void scan3_kernel(
    const float* __restrict__ DELTA, const float* __restrict__ XI,
    const float* __restrict__ DBC, const float* __restrict__ Alog,
    const float* __restrict__ HINIT, const float* __restrict__ XZ,
    const float* __restrict__ Dp, short* __restrict__ G16)
{
  __shared__ __align__(16) float Dl[2][1280], Xl[2][1280], Bl[2][256], Cl[2][256];
  const int tid = threadIdx.x;
  const int lane = tid & 63, wv = tid >> 6;
  const int d = tid >> 2, n4 = tid & 3;
  const int blk = blockIdx.x & 63, chunk = blockIdx.x >> 6;
  const int chain0 = blk * 64;
  const int dir = chain0 >> 11, b = (chain0 >> 9) & 3;
  const int d0 = chain0 & 511;
  const int gd = d0 + d;

  float4 Av = *reinterpret_cast<const float4*>(Alog + ((size_t)(dir * DI + gd)) * 16 + n4 * 4);
  const float An[4] = {-__expf(Av.x), -__expf(Av.y), -__expf(Av.z), -__expf(Av.w)};
  const size_t seq = (size_t)(dir * BB + b) * LL + chunk * CHL;
  const size_t baseDU = seq * DI;
  const size_t baseBC = seq * 48;
  const float Dskip = Dp[dir * DI + gd];

  float4 hi = *reinterpret_cast<const float4*>(
      &HINIT[((size_t)chunk * NCHAIN + chain0 + d) * 16 + n4 * 4]);
  float h[4] = {hi.x, hi.y, hi.z, hi.w};

  const int st = lane & 15, sq = lane >> 4;

  auto stageDX = [&](const float* __restrict__ src, float (*dst)[1280],
                     int w16, int bs, int i) {
    float4 v = *reinterpret_cast<const float4*>(
        src + baseDU + (size_t)(w16 + st) * DI + d0 + i * 16 + sq * 4);
    int dd = i * 16 + sq * 4;
    dst[bs][(dd + 0) * 20 + st] = v.x; dst[bs][(dd + 1) * 20 + st] = v.y;
    dst[bs][(dd + 2) * 20 + st] = v.z; dst[bs][(dd + 3) * 20 + st] = v.w;
  };
  auto stageBC = [&](float (*dst)[256], int off, int w16, int bs) {
    int t = lane >> 2, nq = lane & 3;
    float4 v = *reinterpret_cast<const float4*>(
        DBC + baseBC + (size_t)(w16 + t) * 48 + off + nq * 4);
    *reinterpret_cast<float4*>(&dst[bs][t * 16 + nq * 4]) = v;
  };
  auto stage = [&](int w16, int bs) {
    if (wv == 0)      { stageDX(DELTA, Dl, w16, bs, 0); stageDX(DELTA, Dl, w16, bs, 1); }
    else if (wv == 1) { stageDX(DELTA, Dl, w16, bs, 2); stageDX(DELTA, Dl, w16, bs, 3); }
    else if (wv == 2) { stageDX(XI, Xl, w16, bs, 0); stageDX(XI, Xl, w16, bs, 1); stageBC(Bl, 16, w16, bs); }
    else              { stageDX(XI, Xl, w16, bs, 2); stageDX(XI, Xl, w16, bs, 3); stageBC(Cl, 32, w16, bs); }
  };

  stage(0, 0);
  __syncthreads();

  for (int w = 0; w < CHL / 16; ++w) {
    const int bb = w & 1;
    float rdt[16], ru[16];
#pragma unroll
    for (int q = 0; q < 4; ++q) {
      *reinterpret_cast<float4*>(&rdt[4 * q]) = *reinterpret_cast<const float4*>(&Dl[bb][d * 20 + 4 * q]);
      *reinterpret_cast<float4*>(&ru[4 * q])  = *reinterpret_cast<const float4*>(&Xl[bb][d * 20 + 4 * q]);
    }
    if (w + 1 < CHL / 16) stage((w + 1) * 16, bb ^ 1);
    // direct z loads for this thread's 4 output timesteps (t = n4*4 + j)
    float zq[4];
#pragma unroll
    for (int j = 0; j < 4; ++j)
      zq[j] = XZ[(seq + w * 16 + n4 * 4 + j) * 1024 + 512 + gd];

    float yq[4] = {0.f, 0.f, 0.f, 0.f}, uq[4] = {0.f, 0.f, 0.f, 0.f};
#pragma unroll
    for (int tt = 0; tt < 16; ++tt) {
      float4 rB = *reinterpret_cast<const float4*>(&Bl[bb][tt * 16 + n4 * 4]);
      float4 rC = *reinterpret_cast<const float4*>(&Cl[bb][tt * 16 + n4 * 4]);
      float du = rdt[tt] * ru[tt];
      float bv[4] = {rB.x, rB.y, rB.z, rB.w};
      float cv[4] = {rC.x, rC.y, rC.z, rC.w};
      float p = 0.f;
#pragma unroll
      for (int s = 0; s < 4; ++s) {
        float dA = __expf(rdt[tt] * An[s]);
        h[s] = fmaf(dA, h[s], du * bv[s]);
        p = fmaf(h[s], cv[s], p);
      }
      p = quad_sum(p);                      // full 16-state sum, all 4 lanes
      bool mine = (tt >> 2) == n4;
      yq[tt & 3] = mine ? p : yq[tt & 3];
      uq[tt & 3] = mine ? ru[tt] : uq[tt & 3];
    }
#pragma unroll
    for (int j = 0; j < 4; ++j) {
      float yy = (yq[j] + uq[j] * Dskip) * fsilu(zq[j]);
      G16[baseDU + (size_t)(w * 16 + n4 * 4 + j) * DI + gd] = f2bf(yy);
    }
    __syncthreads();
  }
}

// ---------------------------------------------------------------------------
// dual AddNorm combine: S16 = bf16(LN0(x+f) + LN1(x+bwd)). one block per (b,t).
// ---------------------------------------------------------------------------
__global__ __launch_bounds__(256) void ln_combine_kernel(
    const float* __restrict__ MOUT, const float* __restrict__ x,
    const float* __restrict__ ln_g, const float* __restrict__ ln_b,
    short* __restrict__ S16)
{
  int row = blockIdx.x;
  int m = threadIdx.x;
  size_t i0 = (size_t)row * DM + m;
  float xv = x[i0];
  float s1 = xv + MOUT[i0];
  float s2 = xv + MOUT[(size_t)BL * DM + i0];
  float a1 = s1, q1 = s1 * s1, a2 = s2, q2 = s2 * s2;
  for (int off = 32; off; off >>= 1) {
    a1 += __shfl_xor(a1, off); q1 += __shfl_xor(q1, off);
    a2 += __shfl_xor(a2, off); q2 += __shfl_xor(q2, off);
  }
  __shared__ float red[4][4];
  int w = m >> 6;
  if ((m & 63) == 0) { red[w][0] = a1; red[w][1] = q1; red[w][2] = a2; red[w][3] = q2; }
  __syncthreads();
  a1 = red[0][0] + red[1][0] + red[2][0] + red[3][0];
  q1 = red[0][1] + red[1][1] + red[2][1] + red[3][1];
  a2 = red[0][2] + red[1][2] + red[2][2] + red[3][2];
  q2 = red[0][3] + red[1][3] + red[2][3] + red[3][3];
  const float inv = 1.f / 256.f;
  float mu1 = a1 * inv, mu2 = a2 * inv;
  float v1 = q1 * inv - mu1 * mu1, v2 = q2 * inv - mu2 * mu2;
  float r1 = rsqrtf(v1 + EPSV), r2 = rsqrtf(v2 + EPSV);
  float out = (s1 - mu1) * r1 * ln_g[m] + ln_b[m] +
              (s2 - mu2) * r2 * ln_g[DM + m] + ln_b[DM + m];
  S16[i0] = f2bf(out);
}

}  // namespace

// ---------------------------------------------------------------------------
// workspace (floats):
//   XZ    @ 0          16,777,216  (2,B,L,1024)  [bf16 H16 after scan3]
//   XI    @ 16777216    8,388,608  (2,B,L,512)   [fp32 MOUT after out_proj]
//   DBC   @ 25165824      786,432  (2,B,L,48)
//   DELTA @ 25952256    8,388,608  (2,B,L,512)
//   YS    @ 34340864    8,388,608  [bf16 G16 from scan3; later bf16 S16]
//   X16   @ 42729472    1,048,576  (bf16 x)
//   W16   @ 43778048      655,360  (bf16 weights)
//   HEND  @ 44433408    1,048,576  (16,4096,16)
//   HINIT @ 45481984    1,048,576  (16,4096,16)
//   SDT   @ 46530560       65,536  (16,4096)
// total 46,596,096 floats = 186.4 MB
// ---------------------------------------------------------------------------
extern "C" void kernel_launch(void* const* d_in, const int* in_sizes, int n_in,
                              void* d_out, int out_size, void* d_ws, size_t ws_size,
                              hipStream_t stream) {
  (void)in_sizes; (void)n_in; (void)out_size; (void)ws_size;
  const float* x      = (const float*)d_in[0];
  const float* in_w   = (const float*)d_in[1];
  const float* conv_w = (const float*)d_in[2];
  const float* conv_b = (const float*)d_in[3];
  const float* xproj_w= (const float*)d_in[4];
  const float* dt_w   = (const float*)d_in[5];
  const float* dt_b   = (const float*)d_in[6];
  const float* Alog   = (const float*)d_in[7];
  const float* Dp     = (const float*)d_in[8];
  const float* out_w  = (const float*)d_in[9];
  const float* bn_g   = (const float*)d_in[10];
  const float* bn_b   = (const float*)d_in[11];
  const float* bn_m   = (const float*)d_in[12];
  const float* bn_v   = (const float*)d_in[13];
  const float* ln_g   = (const float*)d_in[14];
  const float* ln_b   = (const float*)d_in[15];
  const float* w1     = (const float*)d_in[16];
  const float* b1     = (const float*)d_in[17];
  const float* w2     = (const float*)d_in[18];
  const float* b2     = (const float*)d_in[19];

  float* ws    = (float*)d_ws;
  float* XZ    = ws;
  float* XI    = ws + 16777216;
  float* DBC   = ws + 25165824;
  float* DELTA = ws + 25952256;
  float* YS    = ws + 34340864;
  short* X16   = (short*)(ws + 42729472);
  short* W16   = (short*)(ws + 43778048);
  short* IN16  = W16;
  short* OUT16 = W16 + 524288;
  short* W1_16 = W16 + 786432;
  short* W2_16 = W16 + 1048576;
  float* HEND  = ws + 44433408;
  float* HINIT = ws + 45481984;
  float* SDT   = ws + 46530560;
  short* G16   = (short*)YS;          // scan3 output (YS region)
  float* MOUT  = XI;                  // XI dead after scan3
  short* S16   = (short*)YS;          // G16 dead after out_proj
  short* H16   = (short*)XZ;          // XZ dead after scan3
  float* OUT   = (float*)d_out;

  dim3 blk(256);

  // 0. bf16 conversions (x + 4 weight tensors, single launch)
  cvt5_kernel<<<3328, blk, 0, stream>>>(x, in_w, out_w, w1, w2,
      X16, IN16, OUT16, W1_16, W2_16);

  // 1. in_proj (both dirs, flip via row map) -> XZ fp32
  mgemm<0><<<dim3(8, 128), blk, 0, stream>>>(X16, IN16, XZ, nullptr, 1024, 256,
      nullptr, nullptr, nullptr, nullptr, nullptr, nullptr);
  // 2. depthwise conv + SiLU -> XI (rolling-window, 8 t/thread)
  conv_silu_kernel<<<1024, blk, 0, stream>>>(XZ, conv_w, conv_b, XI);
  // 3. x_proj -> DBC
  xproj_kernel<<<256, blk, 0, stream>>>(XI, xproj_w, DBC);
  // 4. dt proj + softplus -> DELTA
  dtproj_kernel<<<16384, blk, 0, stream>>>(DBC, dt_w, dt_b, DELTA);
  // 5. chunked SSM scan (4 states/thread), gate fused into pass 3 -> G16
  scan1_kernel<<<960,  blk, 0, stream>>>(DELTA, XI, DBC, Alog, HEND, SDT);
  scan2_kernel<<<256,  blk, 0, stream>>>(HEND, SDT, Alog, HINIT);
  scan3_kernel<<<1024, blk, 0, stream>>>(DELTA, XI, DBC, Alog, HINIT, XZ, Dp, G16);
  // 7. out_proj + BN(dir) + un-flip -> MOUT (fp32, overwrites XI)
  mgemm<1><<<dim3(2, 128), blk, 0, stream>>>(G16, OUT16, MOUT, nullptr, 256, 512,
      bn_g, bn_b, bn_m, bn_v, nullptr, nullptr);
  // 8. dual AddNorm combine -> S16 (bf16, overwrites G16 region)
  ln_combine_kernel<<<8192, blk, 0, stream>>>(MOUT, x, ln_g, ln_b, S16);
  // 9. FF1 (+bias, ReLU) -> H16 (bf16, overwrites XZ)
  mgemm<2><<<dim3(8, 64), blk, 0, stream>>>(S16, W1_16, nullptr, H16, 1024, 256,
      b1, nullptr, nullptr, nullptr, nullptr, nullptr);
  // 10. FF2 (+bias, BN[2], +x) -> OUT fp32
  mgemm<3><<<dim3(2, 64), blk, 0, stream>>>(H16, W2_16, OUT, nullptr, 256, 1024,
      b2, bn_g, bn_b, bn_m, bn_v, x);
}

// Round 8
// 248.908 us; speedup vs baseline: 1.4375x; 1.1025x over previous
//
#include <hip/hip_runtime.h>
#include <hip/hip_bf16.h>
#include <cstdint>
#include <cstddef>

namespace {

constexpr int BB  = 4;      // batch
constexpr int LL  = 2048;   // seq
constexpr int DM  = 256;    // d_model
constexpr int DI  = 512;    // d_inner
constexpr int DFF = 1024;
constexpr float EPSV = 1e-5f;
constexpr int BL  = BB * LL;     // 8192 rows per direction
constexpr int M2  = 2 * BL;      // 16384 rows (both dirs)
constexpr int NCH = 16;          // scan chunks
constexpr int CHL = LL / NCH;    // 128 timesteps per chunk
constexpr int NCHAIN = 2 * BB * DI;   // 4096 scan chains
constexpr int BLDM = BL * DM;         // 2,097,152
constexpr int PL1  = M2 * DM;         // 4,194,304 (out_proj partial plane)
constexpr int PL3  = BL * DM;         // 2,097,152 (ff2 partial plane)

typedef __attribute__((ext_vector_type(8))) short bf16x8;
typedef __attribute__((ext_vector_type(4))) float f32x4;

__device__ __forceinline__ float fsilu(float v) { return v / (1.f + __expf(-v)); }

__device__ __forceinline__ short f2bf(float f) {
  union { float f; uint32_t u; } v; v.f = f;
  uint32_t r = (v.u + 0x7fffu + ((v.u >> 16) & 1u)) >> 16;
  return (short)r;
}

__device__ __forceinline__ void gld16(const short* g, short* l) {
  __builtin_amdgcn_global_load_lds(
      (const __attribute__((address_space(1))) void*)g,
      (__attribute__((address_space(3))) void*)l, 16, 0, 0);
}

// quad (4-lane) sum via DPP quad_perm — pure VALU, no LDS traffic
__device__ __forceinline__ float quad_sum(float v) {
  int a = __builtin_amdgcn_update_dpp(0, __float_as_int(v), 0xB1, 0xF, 0xF, true); // xor1
  v += __int_as_float(a);
  int b = __builtin_amdgcn_update_dpp(0, __float_as_int(v), 0x4E, 0xF, 0xF, true); // xor2
  v += __int_as_float(b);
  return v;
}

// ---------------------------------------------------------------------------
// fused f32 -> bf16 convert for x + 4 weight tensors (one launch)
// ---------------------------------------------------------------------------
__global__ __launch_bounds__(256) void cvt5_kernel(
    const float* __restrict__ s0, const float* __restrict__ s1,
    const float* __restrict__ s2, const float* __restrict__ s3,
    const float* __restrict__ s4,
    short* __restrict__ o0, short* __restrict__ o1, short* __restrict__ o2,
    short* __restrict__ o3, short* __restrict__ o4)
{
  int bid = blockIdx.x;
  const float* s; short* o; int i;
  if (bid < 2048)      { s = s0; o = o0; i = bid; }
  else if (bid < 2560) { s = s1; o = o1; i = bid - 2048; }
  else if (bid < 2816) { s = s2; o = o2; i = bid - 2560; }
  else if (bid < 3072) { s = s3; o = o3; i = bid - 2816; }
  else                 { s = s4; o = o4; i = bid - 3072; }
  int off = (i * 256 + threadIdx.x) * 4;
  float4 v = *reinterpret_cast<const float4*>(s + off);
  ushort4 u;
  u.x = (unsigned short)f2bf(v.x); u.y = (unsigned short)f2bf(v.y);
  u.z = (unsigned short)f2bf(v.z); u.w = (unsigned short)f2bf(v.w);
  *reinterpret_cast<ushort4*>(o + off) = u;
}

// ---------------------------------------------------------------------------
// bf16 MFMA GEMM, 128x128 tile, BK=32, 4 waves of 64x64, fp32 accum.
// Double-buffered LDS: next tile's global_load_lds issued before current
// tile's compute; barrier's vmcnt-drain at iteration end = 2-phase pipeline.
// Split-K via blockIdx.z (K = slice length, lda = full row stride).
// EP 0: in_proj  (time-flip row map, dir by row)    -> raw fp32 XZ
// EP 1: out_proj (dir by row) -> RAW partial plane [z][dir,b,torig][c]
// EP 2: ff1      -> +bias, ReLU, bf16
// EP 3: ff2      -> RAW partial plane [z][row][c]
// ---------------------------------------------------------------------------
template <int EP>
__global__ __launch_bounds__(256) void mgemm(
    const short* __restrict__ A, const short* __restrict__ W,
    float* __restrict__ Cf, short* __restrict__ Ch, int N, int K, int lda,
    const float* __restrict__ P0)
{
  __shared__ short As[2][128 * 32];
  __shared__ short Bs[2][128 * 32];
  const int tid  = threadIdx.x;
  const int lane = tid & 63, wv = tid >> 6;
  const int wrow = (wv >> 1) * 64, wcol = (wv & 1) * 64;
  const int row0 = blockIdx.y * 128, col0 = blockIdx.x * 128;
  const int dir  = (EP == 0 || EP == 1) ? (row0 >= BL ? 1 : 0) : 0;
  const short* Wp = W + (size_t)dir * (size_t)N * (size_t)lda;
  const int koff = blockIdx.z * K;

  auto STAGE = [&](int buf, int kt) {
    int k0 = koff + kt * 32;
#pragma unroll
    for (int s = 0; s < 2; ++s) {
      int f = s * 256 + wv * 64 + lane;      // [0,512)
      int rr = f >> 2, kc = f & 3;           // tile row, 16B chunk along k
      const short* asrc;
      if (EP == 0) {
        int r  = row0 + rr;
        int rb = r & (BL - 1);
        int b = rb >> 11, t = rb & (LL - 1);
        int torig = dir ? (LL - 1 - t) : t;
        asrc = A + ((size_t)(b * LL + torig)) * lda + k0 + kc * 8;
      } else {
        asrc = A + (size_t)(row0 + rr) * lda + k0 + kc * 8;
      }
      const short* bsrc = Wp + (size_t)(col0 + rr) * lda + k0 + kc * 8;
      gld16(asrc, &As[buf][(s * 256 + wv * 64) * 8]);
      gld16(bsrc, &Bs[buf][(s * 256 + wv * 64) * 8]);
    }
  };

  f32x4 acc[4][4];
#pragma unroll
  for (int m = 0; m < 4; ++m)
#pragma unroll
    for (int n = 0; n < 4; ++n) acc[m][n] = (f32x4){0.f, 0.f, 0.f, 0.f};

  STAGE(0, 0);
  __syncthreads();
  const int KT = K / 32;
  for (int kt = 0; kt < KT; ++kt) {
    const int cb = kt & 1;
    if (kt + 1 < KT) STAGE(cb ^ 1, kt + 1);    // overlaps with compute below
    bf16x8 af[4], bfr[4];
    const int krow = (lane >> 4) * 8;
#pragma unroll
    for (int m = 0; m < 4; ++m)
      af[m] = *reinterpret_cast<const bf16x8*>(&As[cb][(wrow + m * 16 + (lane & 15)) * 32 + krow]);
#pragma unroll
    for (int n = 0; n < 4; ++n)
      bfr[n] = *reinterpret_cast<const bf16x8*>(&Bs[cb][(wcol + n * 16 + (lane & 15)) * 32 + krow]);
#pragma unroll
    for (int m = 0; m < 4; ++m)
#pragma unroll
      for (int n = 0; n < 4; ++n)
        acc[m][n] = __builtin_amdgcn_mfma_f32_16x16x32_bf16(af[m], bfr[n], acc[m][n], 0, 0, 0);
    __syncthreads();                            // drains vmcnt -> next buf ready
  }

  // epilogue: C/D layout col=lane&15, row=(lane>>4)*4+reg
#pragma unroll
  for (int m = 0; m < 4; ++m) {
#pragma unroll
    for (int i = 0; i < 4; ++i) {
      int r = row0 + wrow + m * 16 + (lane >> 4) * 4 + i;
      size_t obase;
      if (EP == 1) {
        int rb = r & (BL - 1);
        int b = rb >> 11, t = rb & (LL - 1);
        int torig = dir ? (LL - 1 - t) : t;
        obase = (size_t)blockIdx.z * PL1 +
                ((size_t)(dir * BB + b) * LL + torig) * DM;
      } else if (EP == 3) {
        obase = (size_t)blockIdx.z * PL3 + (size_t)r * DM;
      } else {
        obase = (size_t)r * N;
      }
#pragma unroll
      for (int n = 0; n < 4; ++n) {
        int c = col0 + wcol + n * 16 + (lane & 15);
        float val = acc[m][n][i];
        if (EP == 2) {
          val = fmaxf(val + P0[c], 0.f);
          Ch[obase + c] = f2bf(val);
        } else {
          Cf[obase + c] = val;          // EP0 raw, EP1/EP3 raw partial
        }
      }
    }
  }
}

// ---------------------------------------------------------------------------
// causal depthwise conv (taps=4) + bias + SiLU.
// Register rolling window: thread = (channel-quad, 8 consecutive t).
// ---------------------------------------------------------------------------
__global__ __launch_bounds__(256) void conv_silu_kernel(
    const float* __restrict__ XZ, const float* __restrict__ cw,
    const float* __restrict__ cb, float* __restrict__ XI)
{
  const int bid = blockIdx.x;
  const int db = bid >> 7, tb = bid & 127;     // db = dir*4+b
  const int dir = db >> 2;
  const int tid = threadIdx.x;
  const int dq = (tid & 127) * 4;              // channel quad base
  const int t0 = tb * 16 + (tid >> 7) * 8;     // 8 timesteps per thread
  const size_t base = (size_t)db * LL * 1024 + dq;   // x-half of XZ

  float4 wc0 = *reinterpret_cast<const float4*>(cw + (size_t)(dir * DI + dq + 0) * 4);
  float4 wc1 = *reinterpret_cast<const float4*>(cw + (size_t)(dir * DI + dq + 1) * 4);
  float4 wc2 = *reinterpret_cast<const float4*>(cw + (size_t)(dir * DI + dq + 2) * 4);
  float4 wc3 = *reinterpret_cast<const float4*>(cw + (size_t)(dir * DI + dq + 3) * 4);
  float4 bv  = *reinterpret_cast<const float4*>(cb + dir * DI + dq);

  auto ld = [&](int t) -> float4 {
    if (t < 0) return make_float4(0.f, 0.f, 0.f, 0.f);   // causal zero-pad
    return *reinterpret_cast<const float4*>(XZ + base + (size_t)t * 1024);
  };

  float4 h0 = ld(t0 - 3), h1 = ld(t0 - 2), h2 = ld(t0 - 1);
#pragma unroll
  for (int j = 0; j < 8; ++j) {
    const int t = t0 + j;
    float4 h3 = ld(t);
    float4 o;
    o.x = fsilu(bv.x + wc0.x * h0.x + wc0.y * h1.x + wc0.z * h2.x + wc0.w * h3.x);
    o.y = fsilu(bv.y + wc1.x * h0.y + wc1.y * h1.y + wc1.z * h2.y + wc1.w * h3.y);
    o.z = fsilu(bv.z + wc2.x * h0.z + wc2.y * h1.z + wc2.z * h2.z + wc2.w * h3.z);
    o.w = fsilu(bv.w + wc3.x * h0.w + wc3.y * h1.w + wc3.z * h2.w + wc3.w * h3.w);
    *reinterpret_cast<float4*>(XI + ((size_t)db * LL + t) * DI + dq) = o;
    h0 = h1; h1 = h2; h2 = h3;
  }
}

// ---------------------------------------------------------------------------
// xproj: DBC(M2 x 48) = XI(M2 x 512) @ xproj_w(dir)^T.  64-row tiles, fp32.
// ---------------------------------------------------------------------------
__global__ __launch_bounds__(256) void xproj_kernel(
    const float* __restrict__ XI, const float* __restrict__ W, float* __restrict__ DBC)
{
  __shared__ __align__(16) float As[64 * 68];   // [k][row]
  __shared__ __align__(16) float Ws[64 * 52];   // [k][col]
  const int tid = threadIdx.x;
  const int row0 = blockIdx.x * 64;
  const int dir = row0 >= BL ? 1 : 0;
  const float* Wp = W + (size_t)dir * 48 * DI;
  const int TX = tid & 15, TY = tid >> 4;
  float acc[4][3];
#pragma unroll
  for (int i = 0; i < 4; ++i)
#pragma unroll
    for (int j = 0; j < 3; ++j) acc[i][j] = 0.f;

  for (int k0 = 0; k0 < DI; k0 += 64) {
#pragma unroll
    for (int s = 0; s < 4; ++s) {
      int f = tid + s * 256;
      int kq = f & 15, m = f >> 4;
      float4 v = *reinterpret_cast<const float4*>(XI + (size_t)(row0 + m) * DI + k0 + kq * 4);
      int kk = kq * 4;
      As[(kk + 0) * 68 + m] = v.x; As[(kk + 1) * 68 + m] = v.y;
      As[(kk + 2) * 68 + m] = v.z; As[(kk + 3) * 68 + m] = v.w;
    }
#pragma unroll
    for (int s = 0; s < 3; ++s) {
      int f = tid + s * 256;
      int kq = f & 15, n = f >> 4;
      float4 v = *reinterpret_cast<const float4*>(Wp + (size_t)n * DI + k0 + kq * 4);
      int kk = kq * 4;
      Ws[(kk + 0) * 52 + n] = v.x; Ws[(kk + 1) * 52 + n] = v.y;
      Ws[(kk + 2) * 52 + n] = v.z; Ws[(kk + 3) * 52 + n] = v.w;
    }
    __syncthreads();
    for (int k = 0; k < 64; ++k) {
      float a[4], b[3];
#pragma unroll
      for (int i = 0; i < 4; ++i) a[i] = As[k * 68 + TY * 4 + i];
#pragma unroll
      for (int j = 0; j < 3; ++j) b[j] = Ws[k * 52 + TX * 3 + j];
#pragma unroll
      for (int i = 0; i < 4; ++i)
#pragma unroll
        for (int j = 0; j < 3; ++j) acc[i][j] = fmaf(a[i], b[j], acc[i][j]);
    }
    __syncthreads();
  }
#pragma unroll
  for (int i = 0; i < 4; ++i)
#pragma unroll
    for (int j = 0; j < 3; ++j)
      DBC[(size_t)(row0 + TY * 4 + i) * 48 + TX * 3 + j] = acc[i][j];
}

// ---------------------------------------------------------------------------
// delta = softplus(dt @ dt_w^T + dt_b); one block per (dir,b,t) row
// ---------------------------------------------------------------------------
__global__ __launch_bounds__(256) void dtproj_kernel(
    const float* __restrict__ DBC, const float* __restrict__ dt_w,
    const float* __restrict__ dt_b, float* __restrict__ DELTA)
{
  int row = blockIdx.x;            // [0, 16384)
  int dir = row >> 13;
  __shared__ float dtv[16];
  if (threadIdx.x < 16) dtv[threadIdx.x] = DBC[(size_t)row * 48 + threadIdx.x];
  __syncthreads();
  for (int dd = threadIdx.x; dd < DI; dd += 256) {
    const float* wrow = dt_w + (size_t)(dir * DI + dd) * 16;
    float a = dt_b[dir * DI + dd];
#pragma unroll
    for (int r = 0; r < 16; ++r) a = fmaf(dtv[r], wrow[r], a);
    float sp = (a > 20.f) ? a : log1pf(__expf(a));
    DELTA[(size_t)row * DI + dd] = sp;
  }
}

// ---------------------------------------------------------------------------
// Chunked scan, 4 states/thread (see round-6 notes).
// ---------------------------------------------------------------------------
__global__ __launch_bounds__(256) void scan1_kernel(
    const float* __restrict__ DELTA, const float* __restrict__ XI,
    const float* __restrict__ DBC, const float* __restrict__ Alog,
    float* __restrict__ HEND, float* __restrict__ SDT)
{
  __shared__ __align__(16) float Dl[2][1280], Xl[2][1280], Bl[2][256];
  const int tid = threadIdx.x;
  const int lane = tid & 63, wv = tid >> 6;
  const int d = tid >> 2, n4 = tid & 3;
  const int blk = blockIdx.x & 63, chunk = blockIdx.x >> 6;
  const int chain0 = blk * 64;
  const int dir = chain0 >> 11, b = (chain0 >> 9) & 3;
  const int d0 = chain0 & 511;
  const int gd = d0 + d;

  float4 Av = *reinterpret_cast<const float4*>(Alog + ((size_t)(dir * DI + gd)) * 16 + n4 * 4);
  const float An[4] = {-__expf(Av.x), -__expf(Av.y), -__expf(Av.z), -__expf(Av.w)};
  const size_t seq = (size_t)(dir * BB + b) * LL + chunk * CHL;
  const size_t baseDU = seq * DI;
  const size_t baseBC = seq * 48;

  const int st = lane & 15, sq = lane >> 4;   // stager: t, d-quad-group

  auto stageDX = [&](const float* __restrict__ src, float (*dst)[1280],
                     int w16, int bs, int i) {
    float4 v = *reinterpret_cast<const float4*>(
        src + baseDU + (size_t)(w16 + st) * DI + d0 + i * 16 + sq * 4);
    int dd = i * 16 + sq * 4;
    dst[bs][(dd + 0) * 20 + st] = v.x; dst[bs][(dd + 1) * 20 + st] = v.y;
    dst[bs][(dd + 2) * 20 + st] = v.z; dst[bs][(dd + 3) * 20 + st] = v.w;
  };
  auto stageB = [&](int w16, int bs) {
    int t = lane >> 2, nq = lane & 3;
    float4 v = *reinterpret_cast<const float4*>(
        DBC + baseBC + (size_t)(w16 + t) * 48 + 16 + nq * 4);
    *reinterpret_cast<float4*>(&Bl[bs][t * 16 + nq * 4]) = v;
  };
  auto stage = [&](int w16, int bs) {
    if (wv == 0)      { stageDX(DELTA, Dl, w16, bs, 0); stageDX(DELTA, Dl, w16, bs, 1); }
    else if (wv == 1) { stageDX(DELTA, Dl, w16, bs, 2); stageDX(DELTA, Dl, w16, bs, 3); }
    else if (wv == 2) { stageDX(XI, Xl, w16, bs, 0); stageDX(XI, Xl, w16, bs, 1); }
    else              { stageDX(XI, Xl, w16, bs, 2); stageDX(XI, Xl, w16, bs, 3); stageB(w16, bs); }
  };

  float h[4] = {0.f, 0.f, 0.f, 0.f};
  float sdt = 0.f;
  stage(0, 0);
  __syncthreads();

  for (int w = 0; w < CHL / 16; ++w) {
    const int bb = w & 1;
    float rdt[16], ru[16];
#pragma unroll
    for (int q = 0; q < 4; ++q) {
      *reinterpret_cast<float4*>(&rdt[4 * q]) = *reinterpret_cast<const float4*>(&Dl[bb][d * 20 + 4 * q]);
      *reinterpret_cast<float4*>(&ru[4 * q])  = *reinterpret_cast<const float4*>(&Xl[bb][d * 20 + 4 * q]);
    }
    if (w + 1 < CHL / 16) stage((w + 1) * 16, bb ^ 1);
#pragma unroll
    for (int tt = 0; tt < 16; ++tt) {
      float4 rB = *reinterpret_cast<const float4*>(&Bl[bb][tt * 16 + n4 * 4]);
      float du = rdt[tt] * ru[tt];
      float bv[4] = {rB.x, rB.y, rB.z, rB.w};
#pragma unroll
      for (int s = 0; s < 4; ++s) {
        float dA = __expf(rdt[tt] * An[s]);
        h[s] = fmaf(dA, h[s], du * bv[s]);
      }
      sdt += rdt[tt];
    }
    __syncthreads();
  }
  *reinterpret_cast<float4*>(&HEND[((size_t)chunk * NCHAIN + chain0 + d) * 16 + n4 * 4]) =
      make_float4(h[0], h[1], h[2], h[3]);
  if (n4 == 0) SDT[chunk * NCHAIN + chain0 + d] = sdt;
}

// ---------------------------------------------------------------------------
// pass 2: scan across chunks per chain. grid: 256 blocks.
// ---------------------------------------------------------------------------
__global__ __launch_bounds__(256) void scan2_kernel(
    const float* __restrict__ HEND, const float* __restrict__ SDT,
    const float* __restrict__ Alog, float* __restrict__ HINIT)
{
  const int tid = threadIdx.x;
  const int cl = tid >> 4, n = tid & 15;
  const int chain = blockIdx.x * 16 + cl;
  const int dir = chain >> 11;
  const int d   = chain & 511;
  const float An = -__expf(Alog[((size_t)(dir * DI + d)) * 16 + n]);
  float h = 0.f;
#pragma unroll
  for (int c = 0; c < NCH; ++c) {
    size_t o = ((size_t)c * NCHAIN + chain) * 16 + n;
    HINIT[o] = h;
    float ap = __expf(An * SDT[c * NCHAIN + chain]);
    h = fmaf(ap, h, HEND[o]);
  }
}

// ---------------------------------------------------------------------------
// pass 3: recurrence from HINIT + DPP quad-reduce + fused gate -> G16 bf16.
// ---------------------------------------------------------------------------
__global__ __launch_bounds__(256) void scan3_kernel(
    const float* __restrict__ DELTA, const float* __restrict__ XI,
    const float* __restrict__ DBC, const float* __restrict__ Alog,
    const float* __restrict__ HINIT, const float* __restrict__ XZ,
    const float* __restrict__ Dp, short* __restrict__ G16)
{
  __shared__ __align__(16) float Dl[2][1280], Xl[2][1280], Bl[2][256], Cl[2][256];
  const int tid = threadIdx.x;
  const int lane = tid & 63, wv = tid >> 6;
  const int d = tid >> 2, n4 = tid & 3;
  const int blk = blockIdx.x & 63, chunk = blockIdx.x >> 6;
  const int chain0 = blk * 64;
  const int dir = chain0 >> 11, b = (chain0 >> 9) & 3;
  const int d0 = chain0 & 511;
  const int gd = d0 + d;

  float4 Av = *reinterpret_cast<const float4*>(Alog + ((size_t)(dir * DI + gd)) * 16 + n4 * 4);
  const float An[4] = {-__expf(Av.x), -__expf(Av.y), -__expf(Av.z), -__expf(Av.w)};
  const size_t seq = (size_t)(dir * BB + b) * LL + chunk * CHL;
  const size_t baseDU = seq * DI;
  const size_t baseBC = seq * 48;
  const float Dskip = Dp[dir * DI + gd];

  float4 hi = *reinterpret_cast<const float4*>(
      &HINIT[((size_t)chunk * NCHAIN + chain0 + d) * 16 + n4 * 4]);
  float h[4] = {hi.x, hi.y, hi.z, hi.w};

  const int st = lane & 15, sq = lane >> 4;

  auto stageDX = [&](const float* __restrict__ src, float (*dst)[1280],
                     int w16, int bs, int i) {
    float4 v = *reinterpret_cast<const float4*>(
        src + baseDU + (size_t)(w16 + st) * DI + d0 + i * 16 + sq * 4);
    int dd = i * 16 + sq * 4;
    dst[bs][(dd + 0) * 20 + st] = v.x; dst[bs][(dd + 1) * 20 + st] = v.y;
    dst[bs][(dd + 2) * 20 + st] = v.z; dst[bs][(dd + 3) * 20 + st] = v.w;
  };
  auto stageBC = [&](float (*dst)[256], int off, int w16, int bs) {
    int t = lane >> 2, nq = lane & 3;
    float4 v = *reinterpret_cast<const float4*>(
        DBC + baseBC + (size_t)(w16 + t) * 48 + off + nq * 4);
    *reinterpret_cast<float4*>(&dst[bs][t * 16 + nq * 4]) = v;
  };
  auto stage = [&](int w16, int bs) {
    if (wv == 0)      { stageDX(DELTA, Dl, w16, bs, 0); stageDX(DELTA, Dl, w16, bs, 1); }
    else if (wv == 1) { stageDX(DELTA, Dl, w16, bs, 2); stageDX(DELTA, Dl, w16, bs, 3); }
    else if (wv == 2) { stageDX(XI, Xl, w16, bs, 0); stageDX(XI, Xl, w16, bs, 1); stageBC(Bl, 16, w16, bs); }
    else              { stageDX(XI, Xl, w16, bs, 2); stageDX(XI, Xl, w16, bs, 3); stageBC(Cl, 32, w16, bs); }
  };

  stage(0, 0);
  __syncthreads();

  for (int w = 0; w < CHL / 16; ++w) {
    const int bb = w & 1;
    float rdt[16], ru[16];
#pragma unroll
    for (int q = 0; q < 4; ++q) {
      *reinterpret_cast<float4*>(&rdt[4 * q]) = *reinterpret_cast<const float4*>(&Dl[bb][d * 20 + 4 * q]);
      *reinterpret_cast<float4*>(&ru[4 * q])  = *reinterpret_cast<const float4*>(&Xl[bb][d * 20 + 4 * q]);
    }
    if (w + 1 < CHL / 16) stage((w + 1) * 16, bb ^ 1);
    // direct z loads for this thread's 4 output timesteps (t = n4*4 + j)
    float zq[4];
#pragma unroll
    for (int j = 0; j < 4; ++j)
      zq[j] = XZ[(seq + w * 16 + n4 * 4 + j) * 1024 + 512 + gd];

    float yq[4] = {0.f, 0.f, 0.f, 0.f}, uq[4] = {0.f, 0.f, 0.f, 0.f};
#pragma unroll
    for (int tt = 0; tt < 16; ++tt) {
      float4 rB = *reinterpret_cast<const float4*>(&Bl[bb][tt * 16 + n4 * 4]);
      float4 rC = *reinterpret_cast<const float4*>(&Cl[bb][tt * 16 + n4 * 4]);
      float du = rdt[tt] * ru[tt];
      float bv[4] = {rB.x, rB.y, rB.z, rB.w};
      float cv[4] = {rC.x, rC.y, rC.z, rC.w};
      float p = 0.f;
#pragma unroll
      for (int s = 0; s < 4; ++s) {
        float dA = __expf(rdt[tt] * An[s]);
        h[s] = fmaf(dA, h[s], du * bv[s]);
        p = fmaf(h[s], cv[s], p);
      }
      p = quad_sum(p);                      // full 16-state sum, all 4 lanes
      bool mine = (tt >> 2) == n4;
      yq[tt & 3] = mine ? p : yq[tt & 3];
      uq[tt & 3] = mine ? ru[tt] : uq[tt & 3];
    }
#pragma unroll
    for (int j = 0; j < 4; ++j) {
      float yy = (yq[j] + uq[j] * Dskip) * fsilu(zq[j]);
      G16[baseDU + (size_t)(w * 16 + n4 * 4 + j) * DI + gd] = f2bf(yy);
    }
    __syncthreads();
  }
}

// ---------------------------------------------------------------------------
// dual AddNorm combine with fused out_proj split-K reduce + BN(dir):
// f  = BN0(p0a+p0b); bwd = BN1(p1a+p1b); S16 = bf16(LN0(x+f)+LN1(x+bwd))
// ---------------------------------------------------------------------------
__global__ __launch_bounds__(256) void ln_combine_kernel(
    const float* __restrict__ P1, const float* __restrict__ x,
    const float* __restrict__ bn_g, const float* __restrict__ bn_b,
    const float* __restrict__ bn_m, const float* __restrict__ bn_v,
    const float* __restrict__ ln_g, const float* __restrict__ ln_b,
    short* __restrict__ S16)
{
  int row = blockIdx.x;
  int m = threadIdx.x;
  size_t i0 = (size_t)row * DM + m;
  float xv = x[i0];
  float p0 = P1[i0] + P1[PL1 + i0];                       // dir0: z0+z1
  float p1 = P1[BLDM + i0] + P1[PL1 + BLDM + i0];         // dir1
  float f  = (p0 - bn_m[m]) * rsqrtf(bn_v[m] + EPSV) * bn_g[m] + bn_b[m];
  float bw = (p1 - bn_m[DM + m]) * rsqrtf(bn_v[DM + m] + EPSV) * bn_g[DM + m] + bn_b[DM + m];
  float s1 = xv + f;
  float s2 = xv + bw;
  float a1 = s1, q1 = s1 * s1, a2 = s2, q2 = s2 * s2;
  for (int off = 32; off; off >>= 1) {
    a1 += __shfl_xor(a1, off); q1 += __shfl_xor(q1, off);
    a2 += __shfl_xor(a2, off); q2 += __shfl_xor(q2, off);
  }
  __shared__ float red[4][4];
  int w = m >> 6;
  if ((m & 63) == 0) { red[w][0] = a1; red[w][1] = q1; red[w][2] = a2; red[w][3] = q2; }
  __syncthreads();
  a1 = red[0][0] + red[1][0] + red[2][0] + red[3][0];
  q1 = red[0][1] + red[1][1] + red[2][1] + red[3][1];
  a2 = red[0][2] + red[1][2] + red[2][2] + red[3][2];
  q2 = red[0][3] + red[1][3] + red[2][3] + red[3][3];
  const float inv = 1.f / 256.f;
  float mu1 = a1 * inv, mu2 = a2 * inv;
  float v1 = q1 * inv - mu1 * mu1, v2 = q2 * inv - mu2 * mu2;
  float r1 = rsqrtf(v1 + EPSV), r2 = rsqrtf(v2 + EPSV);
  float out = (s1 - mu1) * r1 * ln_g[m] + ln_b[m] +
              (s2 - mu2) * r2 * ln_g[DM + m] + ln_b[DM + m];
  S16[i0] = f2bf(out);
}

// ---------------------------------------------------------------------------
// ff2 split-K reduce + bias + BN[2] + residual -> OUT fp32. float4/thread.
// grid 2048 x 256 threads.
// ---------------------------------------------------------------------------
__global__ __launch_bounds__(256) void ff2bn_kernel(
    const float* __restrict__ P, const float* __restrict__ fb,
    const float* __restrict__ bn_g, const float* __restrict__ bn_b,
    const float* __restrict__ bn_m, const float* __restrict__ bn_v,
    const float* __restrict__ x, float* __restrict__ OUT)
{
  int idx = blockIdx.x * 256 + threadIdx.x;   // [0, 524288)
  int c = (idx & 63) * 4;
  int row = idx >> 6;
  size_t i0 = (size_t)row * DM + c;
  float4 s0 = *reinterpret_cast<const float4*>(P + i0);
  float4 s1 = *reinterpret_cast<const float4*>(P + PL3 + i0);
  float4 s2 = *reinterpret_cast<const float4*>(P + 2 * (size_t)PL3 + i0);
  float4 s3 = *reinterpret_cast<const float4*>(P + 3 * (size_t)PL3 + i0);
  float4 bb = *reinterpret_cast<const float4*>(fb + c);
  float4 xv = *reinterpret_cast<const float4*>(x + i0);
  float4 g  = *reinterpret_cast<const float4*>(bn_g + 2 * DM + c);
  float4 be = *reinterpret_cast<const float4*>(bn_b + 2 * DM + c);
  float4 mm = *reinterpret_cast<const float4*>(bn_m + 2 * DM + c);
  float4 vv = *reinterpret_cast<const float4*>(bn_v + 2 * DM + c);
  float4 o;
  o.x = (s0.x + s1.x + s2.x + s3.x + bb.x - mm.x) * rsqrtf(vv.x + EPSV) * g.x + be.x + xv.x;
  o.y = (s0.y + s1.y + s2.y + s3.y + bb.y - mm.y) * rsqrtf(vv.y + EPSV) * g.y + be.y + xv.y;
  o.z = (s0.z + s1.z + s2.z + s3.z + bb.z - mm.z) * rsqrtf(vv.z + EPSV) * g.z + be.z + xv.z;
  o.w = (s0.w + s1.w + s2.w + s3.w + bb.w - mm.w) * rsqrtf(vv.w + EPSV) * g.w + be.w + xv.w;
  *reinterpret_cast<float4*>(OUT + i0) = o;
}

}  // namespace

// ---------------------------------------------------------------------------
// workspace (floats):
//   XZ    @ 0          16,777,216  (2,B,L,1024)  [bf16 H16 after scan3]
//   XI    @ 16777216    8,388,608  (2,B,L,512)   [PART1 (2x4.2M) after scan3]
//   DBC   @ 25165824      786,432  (2,B,L,48)
//   DELTA @ 25952256    8,388,608  (2,B,L,512)   [PART3 (4x2.1M) after scan3]
//   YS    @ 34340864    8,388,608  [bf16 G16 from scan3; later bf16 S16]
//   X16   @ 42729472    1,048,576  (bf16 x)
//   W16   @ 43778048      655,360  (bf16 weights)
//   HEND  @ 44433408    1,048,576  (16,4096,16)
//   HINIT @ 45481984    1,048,576  (16,4096,16)
//   SDT   @ 46530560       65,536  (16,4096)
// total 46,596,096 floats = 186.4 MB
// ---------------------------------------------------------------------------
extern "C" void kernel_launch(void* const* d_in, const int* in_sizes, int n_in,
                              void* d_out, int out_size, void* d_ws, size_t ws_size,
                              hipStream_t stream) {
  (void)in_sizes; (void)n_in; (void)out_size; (void)ws_size;
  const float* x      = (const float*)d_in[0];
  const float* in_w   = (const float*)d_in[1];
  const float* conv_w = (const float*)d_in[2];
  const float* conv_b = (const float*)d_in[3];
  const float* xproj_w= (const float*)d_in[4];
  const float* dt_w   = (const float*)d_in[5];
  const float* dt_b   = (const float*)d_in[6];
  const float* Alog   = (const float*)d_in[7];
  const float* Dp     = (const float*)d_in[8];
  const float* out_w  = (const float*)d_in[9];
  const float* bn_g   = (const float*)d_in[10];
  const float* bn_b   = (const float*)d_in[11];
  const float* bn_m   = (const float*)d_in[12];
  const float* bn_v   = (const float*)d_in[13];
  const float* ln_g   = (const float*)d_in[14];
  const float* ln_b   = (const float*)d_in[15];
  const float* w1     = (const float*)d_in[16];
  const float* b1     = (const float*)d_in[17];
  const float* w2     = (const float*)d_in[18];
  const float* b2     = (const float*)d_in[19];

  float* ws    = (float*)d_ws;
  float* XZ    = ws;
  float* XI    = ws + 16777216;
  float* DBC   = ws + 25165824;
  float* DELTA = ws + 25952256;
  float* YS    = ws + 34340864;
  short* X16   = (short*)(ws + 42729472);
  short* W16   = (short*)(ws + 43778048);
  short* IN16  = W16;
  short* OUT16 = W16 + 524288;
  short* W1_16 = W16 + 786432;
  short* W2_16 = W16 + 1048576;
  float* HEND  = ws + 44433408;
  float* HINIT = ws + 45481984;
  float* SDT   = ws + 46530560;
  short* G16   = (short*)YS;          // scan3 output (YS region)
  float* PART1 = XI;                  // out_proj partials (XI dead after scan3)
  float* PART3 = DELTA;               // ff2 partials (DELTA dead after scan3)
  short* S16   = (short*)YS;          // G16 dead after out_proj
  short* H16   = (short*)XZ;          // XZ dead after scan3
  float* OUT   = (float*)d_out;

  dim3 blk(256);

  // 0. bf16 conversions (x + 4 weight tensors, single launch)
  cvt5_kernel<<<3328, blk, 0, stream>>>(x, in_w, out_w, w1, w2,
      X16, IN16, OUT16, W1_16, W2_16);

  // 1. in_proj (both dirs, flip via row map) -> XZ fp32
  mgemm<0><<<dim3(8, 128, 1), blk, 0, stream>>>(X16, IN16, XZ, nullptr,
      1024, 256, 256, nullptr);
  // 2. depthwise conv + SiLU -> XI (rolling-window, 8 t/thread)
  conv_silu_kernel<<<1024, blk, 0, stream>>>(XZ, conv_w, conv_b, XI);
  // 3. x_proj -> DBC
  xproj_kernel<<<256, blk, 0, stream>>>(XI, xproj_w, DBC);
  // 4. dt proj + softplus -> DELTA
  dtproj_kernel<<<16384, blk, 0, stream>>>(DBC, dt_w, dt_b, DELTA);
  // 5. chunked SSM scan (4 states/thread), gate fused into pass 3 -> G16
  scan1_kernel<<<960,  blk, 0, stream>>>(DELTA, XI, DBC, Alog, HEND, SDT);
  scan2_kernel<<<256,  blk, 0, stream>>>(HEND, SDT, Alog, HINIT);
  scan3_kernel<<<1024, blk, 0, stream>>>(DELTA, XI, DBC, Alog, HINIT, XZ, Dp, G16);
  // 7. out_proj split-K x2 -> raw partials PART1 (un-flipped rows)
  mgemm<1><<<dim3(2, 128, 2), blk, 0, stream>>>(G16, OUT16, PART1, nullptr,
      256, 256, 512, nullptr);
  // 8. dual AddNorm combine (+partial reduce +BN(dir)) -> S16
  ln_combine_kernel<<<8192, blk, 0, stream>>>(PART1, x, bn_g, bn_b, bn_m, bn_v,
      ln_g, ln_b, S16);
  // 9. FF1 (+bias, ReLU) -> H16 (bf16, overwrites XZ)
  mgemm<2><<<dim3(8, 64, 1), blk, 0, stream>>>(S16, W1_16, nullptr, H16,
      1024, 256, 256, b1);
  // 10. FF2 split-K x4 -> raw partials PART3
  mgemm<3><<<dim3(2, 64, 4), blk, 0, stream>>>(H16, W2_16, PART3, nullptr,
      256, 256, 1024, nullptr);
  // 11. ff2 reduce + bias + BN[2] + residual -> OUT
  ff2bn_kernel<<<2048, blk, 0, stream>>>(PART3, b2, bn_g, bn_b, bn_m, bn_v,
      x, OUT);
}